// Round 2
// baseline (333.245 us; speedup 1.0000x reference)
//
#include <hip/hip_runtime.h>
#include <math.h>

typedef unsigned short u16;
typedef unsigned int u32;
typedef unsigned long long u64;
typedef __attribute__((ext_vector_type(8))) _Float16 f16x8;
typedef __attribute__((ext_vector_type(2))) _Float16 f16x2;
typedef __attribute__((ext_vector_type(4))) float f32x4;

union U8h { f16x8 v; f16x2 p[4]; u32 u[4]; _Float16 s[8]; };
union U4h { _Float16 s[4]; u64 u; };

__device__ __forceinline__ void atomicMaxF(float* addr, float val) {
  if (val >= 0.0f) {
    atomicMax((int*)addr, __float_as_int(val));
  } else {
    atomicMin((unsigned int*)addr, (unsigned int)__float_as_int(val));
  }
}

__device__ __forceinline__ f16x2 pk(float a, float b) {
  return __builtin_bit_cast(f16x2, __builtin_amdgcn_cvt_pkrtz(a, b));
}

// split 8 fp32 -> fp16 hi (RTZ) + lo (residual): hi+lo exact to ~2^-22
__device__ __forceinline__ void dec8h(const float* f, U8h& h, U8h& l) {
#pragma unroll
  for (int i = 0; i < 4; ++i) {
    float a = f[2 * i], b = f[2 * i + 1];
    f16x2 hp = pk(a, b);
    float ra = a - (float)hp[0];
    float rb = b - (float)hp[1];
    h.p[i] = hp;
    l.p[i] = pk(ra, rb);
  }
}

__device__ __forceinline__ void conv8_rne(const float* f, U8h& h) {
#pragma unroll
  for (int i = 0; i < 8; ++i) h.s[i] = (_Float16)f[i];
}

// lane's two 8-float chunks of a 64-float row from GLOBAL memory (no swizzle)
__device__ __forceinline__ void load_row(const float* p, float* f) {
  *(float4*)(f + 0)  = *(const float4*)(p);
  *(float4*)(f + 4)  = *(const float4*)(p + 4);
  *(float4*)(f + 8)  = *(const float4*)(p + 32);
  *(float4*)(f + 12) = *(const float4*)(p + 36);
}

// ---- XOR-swizzled [16][64] fp32 LDS slice (4096 B, bank-conflict-reduced) ----
__device__ __forceinline__ int swz(int row, int col) {
  return (row << 6) + (col ^ ((row & 7) << 2));
}

// read row m, cols q*8..+7 and 32+q*8..+7 (swizzled)
__device__ __forceinline__ void load_row_swz(const float* hb, int m, int q, float* f) {
  int s = (m & 7) << 2;
  const float* r = hb + (m << 6);
  *(float4*)(f + 0)  = *(const float4*)(r + ((q * 8)      ^ s));
  *(float4*)(f + 4)  = *(const float4*)(r + ((q * 8 + 4)  ^ s));
  *(float4*)(f + 8)  = *(const float4*)(r + ((q * 8 + 32) ^ s));
  *(float4*)(f + 12) = *(const float4*)(r + ((q * 8 + 36) ^ s));
}

// read row m, 16 consecutive cols starting at c0 (multiple of 4)
__device__ __forceinline__ void load_16_swz(const float* hb, int m, int c0, float* f) {
  int s = (m & 7) << 2;
  const float* r = hb + (m << 6);
#pragma unroll
  for (int j = 0; j < 4; ++j)
    *(float4*)(f + 4 * j) = *(const float4*)(r + ((c0 + 4 * j) ^ s));
}

// ---- cross-q segmented-run merge for dst-sorted scatter-max ----
struct RunCtx { bool chain1, chain2, chain3, suppress; };

__device__ __forceinline__ RunCtx run_ctx(const int dd[4], int lane, int q) {
  bool allsame = (dd[0] == dd[1]) && (dd[1] == dd[2]) && (dd[2] == dd[3]);
  int nfd1 = __shfl(dd[0], lane + 16, 64);
  int nfd2 = __shfl(dd[0], lane + 32, 64);
  int nfd3 = __shfl(dd[0], lane + 48, 64);
  int as = allsame ? 1 : 0;
  int nas1 = __shfl(as, lane + 16, 64);
  int nas2 = __shfl(as, lane + 32, 64);
  int pld = __shfl(dd[3], lane - 16, 64);
  RunCtx c;
  c.chain1 = (q < 3) && (nfd1 == dd[3]);
  c.chain2 = c.chain1 && (nas1 != 0) && (q < 2) && (nfd2 == dd[3]);
  c.chain3 = c.chain2 && (nas2 != 0) && (q < 1) && (nfd3 == dd[3]);
  c.suppress = (q > 0) && (pld == dd[0]);
  return c;
}

__device__ __forceinline__ void emit_t(const f32x4 o, const int dd[4], const RunCtx c,
                                       int lane, int m, int t, float* __restrict__ xnew) {
  float fv = o[0];
  bool c01 = dd[1] == dd[0];
  fv = c01 ? fmaxf(fv, o[1]) : fv;
  bool c012 = c01 && (dd[2] == dd[1]);
  fv = c012 ? fmaxf(fv, o[2]) : fv;
  bool c0123 = c012 && (dd[3] == dd[2]);
  fv = c0123 ? fmaxf(fv, o[3]) : fv;
  float nfv1 = __shfl(fv, lane + 16, 64);
  float nfv2 = __shfl(fv, lane + 32, 64);
  float nfv3 = __shfl(fv, lane + 48, 64);
  float run = o[0];
  bool first = true;
#pragma unroll
  for (int r = 0; r < 4; ++r) {
    if (r > 0) run = (dd[r] == dd[r - 1]) ? fmaxf(run, o[r]) : o[r];
    bool end = (r == 3) || (dd[r + 1] != dd[r]);
    if (end) {
      float val = run;
      if (r == 3) {
        if (c.chain1) val = fmaxf(val, nfv1);
        if (c.chain2) val = fmaxf(val, nfv2);
        if (c.chain3) val = fmaxf(val, nfv3);
      }
      if (!(first && c.suppress) && dd[r] >= 0)
        atomicMaxF(&xnew[(size_t)dd[r] * 64 + t * 16 + m], val);
      first = false;
    }
  }
}

// ---------------- vcp build + degree histogram + goal argmax (fused) ----------------
__global__ __launch_bounds__(256) void k_vch(const float* __restrict__ v,
                                             const float* __restrict__ labels,
                                             float* __restrict__ vcp, int N,
                                             const int* __restrict__ dst, int E,
                                             int* __restrict__ deg, u64* __restrict__ key) {
  int tid = blockIdx.x * 256 + threadIdx.x;
  if (tid < N * 16) {
    int n = tid >> 4, c = tid & 15;
    float val = 0.f;
    if (c < 7) val = v[(size_t)n * 7 + c];
    else if (c == 7) val = labels[2 * (size_t)n];
    else if (c == 8) val = labels[2 * (size_t)n + 1];
    vcp[tid] = val;
  }
  if (tid < E) atomicAdd(&deg[dst[tid]], 1);
  if ((tid & ~63) < N) {
    float val = (tid < N) ? labels[2 * (size_t)tid + 1] : 0.0f;
    u64 k = ((u64)__float_as_uint(fmaxf(val, 0.0f)) << 32) | (u32)(~(u32)tid);
#pragma unroll
    for (int off = 32; off > 0; off >>= 1) {
      u64 o = __shfl_xor(k, off, 64);
      if (o > k) k = o;
    }
    if ((threadIdx.x & 63) == 0) atomicMax(key, k);
  }
}

// ---------------- weight prep (+ deg/goalkey zero init) ----------------
__global__ __launch_bounds__(256) void k_prep(const float* __restrict__ fxw1, const float* __restrict__ fxw2,
                                              const float* __restrict__ fyw1, const float* __restrict__ fyw2,
                                              const float* __restrict__ hyw1, const float* __restrict__ hyw2,
                                              const float* __restrict__ hxw1, const float* __restrict__ hxw2,
                                              const float* __restrict__ few1, const float* __restrict__ few2,
                                              _Float16* __restrict__ wp, u64* __restrict__ goalkey,
                                              int* __restrict__ deg, int N) {
  int tid = blockIdx.x * 256 + threadIdx.x;
  if (tid == 0) *goalkey = 0;
  for (int i = tid; i < N; i += gridDim.x * 256) deg[i] = 0;
  _Float16* fxB1 = wp;           // 12288
  _Float16* fxB2 = wp + 12288;   // 4096
  _Float16* fyB1 = wp + 16384;   // 8192
  _Float16* fyB2 = wp + 24576;   // 4096
  _Float16* hyB1 = wp + 28672;   // 2048
  _Float16* hyB2 = wp + 30720;   // 4096
  _Float16* hxB1 = wp + 34816;   // 2048
  _Float16* hxB2 = wp + 36864;   // 4096
  _Float16* feB1 = wp + 40960;   // 4096
  _Float16* feB2 = wp + 45056;   // 4096
  int which, id;
  _Float16* oh;
  if (tid < 1536)      { which = 0; id = tid;        oh = fxB1; }
  else if (tid < 2048) { which = 1; id = tid - 1536; oh = fxB2; }
  else if (tid < 3072) { which = 2; id = tid - 2048; oh = fyB1; }
  else if (tid < 3584) { which = 3; id = tid - 3072; oh = fyB2; }
  else if (tid < 3840) { which = 4; id = tid - 3584; oh = hyB1; }
  else if (tid < 4352) { which = 5; id = tid - 3840; oh = hyB2; }
  else if (tid < 4608) { which = 6; id = tid - 4352; oh = hxB1; }
  else if (tid < 5120) { which = 7; id = tid - 4608; oh = hxB2; }
  else if (tid < 5632) { which = 8; id = tid - 5120; oh = feB1; }
  else if (tid < 6144) { which = 9; id = tid - 5632; oh = feB2; }
  else return;
  int lane = id & 63;
  int q = lane >> 4, col = lane & 15;
  int c = id >> 8, t = (id >> 6) & 3;
#pragma unroll
  for (int j = 0; j < 8; ++j) {
    int k = c * 32 + q * 8 + j;
    int n = t * 16 + col;
    float w;
    if (which == 0) {
      w = (k < 64)  ? fxw1[k * 64 + n] + fxw1[(k + 64) * 64 + n]
        : (k < 128) ? fxw1[(k + 64) * 64 + n] - fxw1[(k - 64) * 64 + n]
                    : fxw1[(k + 64) * 64 + n];
    } else if (which == 1) {
      w = fxw2[k * 64 + n];
    } else if (which == 2) {
      w = (k < 64) ? fyw1[k * 64 + n] + fyw1[(k + 64) * 64 + n]
                   : fyw1[(k + 64) * 64 + n] - fyw1[(k - 64) * 64 + n];
    } else if (which == 3) {
      w = fyw2[k * 64 + n];
    } else if (which == 4) {
      if (k <= 8)                  w = hyw1[k * 64 + n] + hyw1[(k + 9) * 64 + n];
      else if (k >= 16 && k <= 24) w = hyw1[(k + 2) * 64 + n] - hyw1[(k - 16) * 64 + n];
      else                         w = 0.f;
    } else if (which == 5) {
      w = hyw2[k * 64 + n];
    } else if (which == 6) {
      w = (k < 9) ? hxw1[k * 64 + n] : (k < 27) ? hxw1[(k + 9) * 64 + n] : 0.f;
    } else if (which == 7) {
      w = hxw2[k * 64 + n];
    } else if (which == 8) {
      w = few1[k * 64 + n];
    } else {
      w = few2[k * 64 + n];
    }
    oh[id * 8 + j] = (_Float16)w;
  }
}

// ---------------- scan1 + goal2b merged (both depend only on k_vch) ----------------
__global__ __launch_bounds__(256) void k_scan1g(const int* __restrict__ deg, int N, int SB,
                                                int* __restrict__ bsum,
                                                const float* __restrict__ v,
                                                const float* __restrict__ labels,
                                                const u64* __restrict__ key,
                                                const float* __restrict__ hxw1,
                                                const float* __restrict__ hxb1,
                                                float* __restrict__ goal, float* __restrict__ b1p) {
  int b = blockIdx.x;
  if (b >= SB) {
    __shared__ float g[9];
    int gi = (int)(~(u32)(*key));
    int c = threadIdx.x;
    if (c < 9) {
      float gv = (c < 7) ? v[7 * (size_t)gi + c] : labels[2 * (size_t)gi + (c - 7)];
      g[c] = gv;
      goal[c] = gv;
    }
    __syncthreads();
    if (c < 64) {
      float s = hxb1[c];
#pragma unroll
      for (int k = 0; k < 9; ++k) s += g[k] * hxw1[(9 + k) * 64 + c];
      b1p[c] = s;
    }
    return;
  }
  __shared__ int red[256];
  int s = 0;
  for (int i = threadIdx.x; i < 1024; i += 256) {
    int idx = b * 1024 + i;
    s += (idx < N) ? deg[idx] : 0;
  }
  red[threadIdx.x] = s; __syncthreads();
  for (int st = 128; st > 0; st >>= 1) {
    if (threadIdx.x < st) red[threadIdx.x] += red[threadIdx.x + st];
    __syncthreads();
  }
  if (threadIdx.x == 0) bsum[b] = red[0];
}

// ---------------- hx (MFMA) + scan3 merged ----------------
__global__ __launch_bounds__(256) void k_hx2s(
    const float* __restrict__ vcp, const float* __restrict__ goal,
    const _Float16* __restrict__ B1, const float* __restrict__ b1p,
    const _Float16* __restrict__ B2, const float* __restrict__ b2,
    float* __restrict__ xout, _Float16* __restrict__ xh, int N,
    const int* __restrict__ deg, const int* __restrict__ bsum, int* __restrict__ cursor, int NB) {
  if ((int)blockIdx.x >= NB) {
    // ---- scan3 ----
    __shared__ int lsum[256];
    __shared__ int bofs;
    int b = blockIdx.x - NB;
    int tid = threadIdx.x;
    if (tid == 0) {
      int a = 0;
      for (int i = 0; i < b; ++i) a += bsum[i];
      bofs = a;
    }
    int base_i = b * 1024 + tid * 4;
    int loc[4]; int s = 0;
#pragma unroll
    for (int j = 0; j < 4; ++j) {
      int vv = (base_i + j < N) ? deg[base_i + j] : 0;
      loc[j] = s; s += vv;
    }
    lsum[tid] = s; __syncthreads();
    for (int st = 1; st < 256; st <<= 1) {
      int add = (tid >= st) ? lsum[tid - st] : 0;
      __syncthreads();
      lsum[tid] += add;
      __syncthreads();
    }
    int toff = bofs + lsum[tid] - s;
#pragma unroll
    for (int j = 0; j < 4; ++j) {
      if (base_i + j < N) cursor[base_i + j] = toff + loc[j];
    }
    return;
  }
  // ---- hx ----
  __shared__ float hbuf[4][16 * 64];
  const int lane = threadIdx.x & 63;
  const int wv = threadIdx.x >> 6;
  const int m = lane & 15, q = lane >> 4;
  const int base = blockIdx.x * 64 + wv * 16;
  int node = base + m; if (node >= N) node = N - 1;
  float vc[12];
  *(float4*)(vc + 0) = *(const float4*)(vcp + (size_t)node * 16);
  *(float4*)(vc + 4) = *(const float4*)(vcp + (size_t)node * 16 + 4);
  *(float4*)(vc + 8) = *(const float4*)(vcp + (size_t)node * 16 + 8);
  float gl[9];
#pragma unroll
  for (int i = 0; i < 9; ++i) gl[i] = goal[i];
  float f[8];
#pragma unroll
  for (int j = 0; j < 8; ++j) {
    int idx = q * 8 + j;
    float val = 0.f;
    if (idx < 9) val = vc[idx];
    else if (idx < 18) val = vc[idx - 9] - gl[idx - 9];
    else if (idx < 27) { float dv = vc[idx - 18] - gl[idx - 18]; val = dv * dv; }
    f[j] = val;
  }
  U8h Ah, Al;
  dec8h(f, Ah, Al);

  f32x4 acc[4];
#pragma unroll
  for (int t = 0; t < 4; ++t) { float bv = b1p[t * 16 + m]; acc[t] = (f32x4){bv, bv, bv, bv}; }
#pragma unroll
  for (int t = 0; t < 4; ++t) {
    f16x8 b = *(const f16x8*)(B1 + ((size_t)t * 64 + lane) * 8);
    acc[t] = __builtin_amdgcn_mfma_f32_16x16x32_f16(Ah.v, b, acc[t], 0, 0, 0);
    acc[t] = __builtin_amdgcn_mfma_f32_16x16x32_f16(Al.v, b, acc[t], 0, 0, 0);
  }

  float* hb = hbuf[wv];
#pragma unroll
  for (int t = 0; t < 4; ++t)
#pragma unroll
    for (int r = 0; r < 4; ++r)
      hb[swz(q * 4 + r, t * 16 + m)] = fmaxf(acc[t][r], 0.f);

  float fh[16];
  load_row_swz(hb, m, q, fh);
  U8h A2h[2], A2l[2];
  dec8h(fh + 0, A2h[0], A2l[0]);
  dec8h(fh + 8, A2h[1], A2l[1]);

  f32x4 acc2[4];
#pragma unroll
  for (int t = 0; t < 4; ++t) { float bv = b2[t * 16 + m]; acc2[t] = (f32x4){bv, bv, bv, bv}; }
#pragma unroll
  for (int c = 0; c < 2; ++c) {
#pragma unroll
    for (int t = 0; t < 4; ++t) {
      f16x8 b = *(const f16x8*)(B2 + ((size_t)(c * 4 + t) * 64 + lane) * 8);
      acc2[t] = __builtin_amdgcn_mfma_f32_16x16x32_f16(A2h[c].v, b, acc2[t], 0, 0, 0);
      acc2[t] = __builtin_amdgcn_mfma_f32_16x16x32_f16(A2l[c].v, b, acc2[t], 0, 0, 0);
    }
  }

#pragma unroll
  for (int t = 0; t < 4; ++t)
#pragma unroll
    for (int r = 0; r < 4; ++r)
      hb[swz(q * 4 + r, t * 16 + m)] = acc2[t][r];

  int row = base + m;
  if (row < N) {
    float ov[16];
    load_16_swz(hb, m, q * 16, ov);
    float* p1 = xout + (size_t)row * 64 + q * 16;
#pragma unroll
    for (int i = 0; i < 4; ++i) {
      *(float4*)(p1 + i * 4) = *(const float4*)(ov + i * 4);
    }
    U8h X0, X1;
    conv8_rne(ov + 0, X0);
    conv8_rne(ov + 8, X1);
    *(f16x8*)(xh + (size_t)row * 64 + q * 16)     = X0.v;
    *(f16x8*)(xh + (size_t)row * 64 + q * 16 + 8) = X1.v;
  }
}

__global__ __launch_bounds__(256) void k_scatter(const int* __restrict__ src,
                                                 const int* __restrict__ dst, int E,
                                                 int* __restrict__ cursor,
                                                 int* __restrict__ srcp, int* __restrict__ dstp) {
  int e = blockIdx.x * 256 + threadIdx.x;
  if (e < E) {
    int d = dst[e];
    int pos = atomicAdd(&cursor[d], 1);
    srcp[pos] = src[e];
    dstp[pos] = d;
  }
}

// ---------------- convert: fp16 gather shadow from fp32 x (in-place atomics; no copy) ----------------
__global__ __launch_bounds__(256) void k_ch(const float4* __restrict__ s,
                                            _Float16* __restrict__ h16, int n4) {
  int i = blockIdx.x * 256 + threadIdx.x;
  if (i < n4) {
    float4 v = s[i];
    U4h o;
    o.s[0] = (_Float16)v.x; o.s[1] = (_Float16)v.y;
    o.s[2] = (_Float16)v.z; o.s[3] = (_Float16)v.w;
    *(u64*)(h16 + (size_t)i * 4) = o.u;
  }
}

// ---------------- fused hy + fx (t=0): 2 independent 16-edge tiles per wave ----------------
__global__ __launch_bounds__(256) void k_hyfx(
    const float* __restrict__ vcp, const _Float16* __restrict__ xh,
    const int* __restrict__ src, const int* __restrict__ dst,
    const _Float16* __restrict__ hB1, const float* __restrict__ hb1,
    const _Float16* __restrict__ hB2, const float* __restrict__ hb2,
    const _Float16* __restrict__ xB1, const float* __restrict__ xb1,
    const _Float16* __restrict__ xB2, const float* __restrict__ xb2,
    _Float16* __restrict__ y, float* __restrict__ xnew, int E) {
  __shared__ float hbuf[8][16 * 64];
  const int lane = threadIdx.x & 63;
  const int wv = threadIdx.x >> 6;
  const int m = lane & 15, q = lane >> 4;
  const int b0e = blockIdx.x * 128 + wv * 16;
  float* hb0 = hbuf[wv];
  float* hbx = hbuf[4 + wv];

  int em0 = b0e + m;       if (em0 >= E) em0 = E - 1;
  int em1 = b0e + 64 + m;  if (em1 >= E) em1 = E - 1;
  const int si0 = src[em0], di0 = dst[em0];
  const int si1 = src[em1], di1 = dst[em1];
  const bool live0 = (b0e + m) < E;
  const bool live1 = (b0e + 64 + m) < E;

  U8h Xs0[2], Xs1[2], Xd0[2], Xd1[2];
  {
    const _Float16* ps = xh + (size_t)si0 * 64 + q * 8;
    const _Float16* pd = xh + (size_t)di0 * 64 + q * 8;
    Xs0[0].v = *(const f16x8*)ps;  Xs1[0].v = *(const f16x8*)(ps + 32);
    Xd0[0].v = *(const f16x8*)pd;  Xd1[0].v = *(const f16x8*)(pd + 32);
  }
  {
    const _Float16* ps = xh + (size_t)si1 * 64 + q * 8;
    const _Float16* pd = xh + (size_t)di1 * 64 + q * 8;
    Xs0[1].v = *(const f16x8*)ps;  Xs1[1].v = *(const f16x8*)(ps + 32);
    Xd0[1].v = *(const f16x8*)pd;  Xd1[1].v = *(const f16x8*)(pd + 32);
  }

  // hy A inputs (vcp of di for q<2, si for q>=2)
  U8h Ah[2], Al[2];
  {
    const int n0 = (q < 2) ? di0 : si0;
    const float* p = vcp + (size_t)n0 * 16 + (q & 1) * 8;
    float f[8];
    *(float4*)(f + 0) = *(const float4*)(p);
    *(float4*)(f + 4) = *(const float4*)(p + 4);
    dec8h(f, Ah[0], Al[0]);
  }
  {
    const int n1 = (q < 2) ? di1 : si1;
    const float* p = vcp + (size_t)n1 * 16 + (q & 1) * 8;
    float f[8];
    *(float4*)(f + 0) = *(const float4*)(p);
    *(float4*)(f + 4) = *(const float4*)(p + 4);
    dec8h(f, Ah[1], Al[1]);
  }

  // ---- hy layer 1 ----
  f32x4 acc[2][4];
#pragma unroll
  for (int t = 0; t < 4; ++t) {
    float bv = hb1[t * 16 + m];
    acc[0][t] = (f32x4){bv, bv, bv, bv};
    acc[1][t] = acc[0][t];
  }
#pragma unroll
  for (int t = 0; t < 4; ++t) {
    f16x8 w = *(const f16x8*)(hB1 + ((size_t)t * 64 + lane) * 8);
#pragma unroll
    for (int u = 0; u < 2; ++u) {
      acc[u][t] = __builtin_amdgcn_mfma_f32_16x16x32_f16(Ah[u].v, w, acc[u][t], 0, 0, 0);
      acc[u][t] = __builtin_amdgcn_mfma_f32_16x16x32_f16(Al[u].v, w, acc[u][t], 0, 0, 0);
    }
  }

#pragma unroll
  for (int t = 0; t < 4; ++t)
#pragma unroll
    for (int r = 0; r < 4; ++r) {
      hb0[swz(q * 4 + r, t * 16 + m)] = fmaxf(acc[0][t][r], 0.f);
      hbx[swz(q * 4 + r, t * 16 + m)] = fmaxf(acc[1][t][r], 0.f);
    }

  float fh0[16], fh1[16];
  load_row_swz(hb0, m, q, fh0);
  load_row_swz(hbx, m, q, fh1);
  U8h H0[2], H1[2];
  conv8_rne(fh0 + 0, H0[0]); conv8_rne(fh0 + 8, H1[0]);
  conv8_rne(fh1 + 0, H0[1]); conv8_rne(fh1 + 8, H1[1]);

  // ---- hy layer 2 ----
  f32x4 o[2][4];
#pragma unroll
  for (int t = 0; t < 4; ++t) {
    float bv = hb2[t * 16 + m];
    o[0][t] = (f32x4){bv, bv, bv, bv};
    o[1][t] = o[0][t];
  }
#pragma unroll
  for (int t = 0; t < 4; ++t) {
    f16x8 w0 = *(const f16x8*)(hB2 + ((size_t)(0 * 4 + t) * 64 + lane) * 8);
    f16x8 w1 = *(const f16x8*)(hB2 + ((size_t)(1 * 4 + t) * 64 + lane) * 8);
#pragma unroll
    for (int u = 0; u < 2; ++u) {
      o[u][t] = __builtin_amdgcn_mfma_f32_16x16x32_f16(H0[u].v, w0, o[u][t], 0, 0, 0);
      o[u][t] = __builtin_amdgcn_mfma_f32_16x16x32_f16(H1[u].v, w1, o[u][t], 0, 0, 0);
    }
  }

#pragma unroll
  for (int t = 0; t < 4; ++t)
#pragma unroll
    for (int r = 0; r < 4; ++r) {
      hb0[swz(q * 4 + r, t * 16 + m)] = o[0][t][r];
      hbx[swz(q * 4 + r, t * 16 + m)] = o[1][t][r];
    }

  float nv0[16], nv1[16];
  load_row_swz(hb0, m, q, nv0);
  load_row_swz(hbx, m, q, nv1);
  U8h Yh0[2], Yh1[2];
  conv8_rne(nv0 + 0, Yh0[0]); conv8_rne(nv0 + 8, Yh1[0]);
  conv8_rne(nv1 + 0, Yh0[1]); conv8_rne(nv1 + 8, Yh1[1]);
  if (live0) {
    size_t yo = (size_t)(b0e + m) * 64 + q * 8;
    *(f16x8*)(y + yo)      = Yh0[0].v;
    *(f16x8*)(y + yo + 32) = Yh1[0].v;
  }
  if (live1) {
    size_t yo = (size_t)(b0e + 64 + m) * 64 + q * 8;
    *(f16x8*)(y + yo)      = Yh0[1].v;
    *(f16x8*)(y + yo + 32) = Yh1[1].v;
  }

  // ---- fx layer 1 ----
  f32x4 acc2[2][4];
#pragma unroll
  for (int t = 0; t < 4; ++t) {
    float bv = xb1[t * 16 + m];
    acc2[0][t] = (f32x4){bv, bv, bv, bv};
    acc2[1][t] = acc2[0][t];
  }
#pragma unroll
  for (int t = 0; t < 4; ++t) {
    f16x8 w0 = *(const f16x8*)(xB1 + ((size_t)(0 * 4 + t) * 64 + lane) * 8);
    f16x8 w1 = *(const f16x8*)(xB1 + ((size_t)(1 * 4 + t) * 64 + lane) * 8);
    f16x8 w2 = *(const f16x8*)(xB1 + ((size_t)(2 * 4 + t) * 64 + lane) * 8);
    f16x8 w3 = *(const f16x8*)(xB1 + ((size_t)(3 * 4 + t) * 64 + lane) * 8);
    f16x8 w4 = *(const f16x8*)(xB1 + ((size_t)(4 * 4 + t) * 64 + lane) * 8);
    f16x8 w5 = *(const f16x8*)(xB1 + ((size_t)(5 * 4 + t) * 64 + lane) * 8);
#pragma unroll
    for (int u = 0; u < 2; ++u) {
      acc2[u][t] = __builtin_amdgcn_mfma_f32_16x16x32_f16(Xs0[u].v, w0, acc2[u][t], 0, 0, 0);
      acc2[u][t] = __builtin_amdgcn_mfma_f32_16x16x32_f16(Xs1[u].v, w1, acc2[u][t], 0, 0, 0);
      acc2[u][t] = __builtin_amdgcn_mfma_f32_16x16x32_f16(Xd0[u].v, w2, acc2[u][t], 0, 0, 0);
      acc2[u][t] = __builtin_amdgcn_mfma_f32_16x16x32_f16(Xd1[u].v, w3, acc2[u][t], 0, 0, 0);
      acc2[u][t] = __builtin_amdgcn_mfma_f32_16x16x32_f16(Yh0[u].v, w4, acc2[u][t], 0, 0, 0);
      acc2[u][t] = __builtin_amdgcn_mfma_f32_16x16x32_f16(Yh1[u].v, w5, acc2[u][t], 0, 0, 0);
    }
  }

#pragma unroll
  for (int t = 0; t < 4; ++t)
#pragma unroll
    for (int r = 0; r < 4; ++r) {
      hb0[swz(q * 4 + r, t * 16 + m)] = fmaxf(acc2[0][t][r], 0.f);
      hbx[swz(q * 4 + r, t * 16 + m)] = fmaxf(acc2[1][t][r], 0.f);
    }

  float g0v[16], g1v[16];
  load_row_swz(hb0, m, q, g0v);
  load_row_swz(hbx, m, q, g1v);
  U8h G0[2], G1[2];
  conv8_rne(g0v + 0, G0[0]); conv8_rne(g0v + 8, G1[0]);
  conv8_rne(g1v + 0, G0[1]); conv8_rne(g1v + 8, G1[1]);

  // dst loads for emit (deferred)
  int dd0[4], dd1[4];
  {
    int e0 = b0e + q * 4;
#pragma unroll
    for (int r = 0; r < 4; ++r) {
      int e2 = e0 + r;
      dd0[r] = (e2 < E) ? dst[e2] : -1;
      int e3 = e2 + 64;
      dd1[r] = (e3 < E) ? dst[e3] : -1;
    }
  }

  // ---- fx layer 2 ----
  f32x4 o2[2][4];
#pragma unroll
  for (int t = 0; t < 4; ++t) {
    float bv = xb2[t * 16 + m];
    o2[0][t] = (f32x4){bv, bv, bv, bv};
    o2[1][t] = o2[0][t];
  }
#pragma unroll
  for (int t = 0; t < 4; ++t) {
    f16x8 w0 = *(const f16x8*)(xB2 + ((size_t)(0 * 4 + t) * 64 + lane) * 8);
    f16x8 w1 = *(const f16x8*)(xB2 + ((size_t)(1 * 4 + t) * 64 + lane) * 8);
#pragma unroll
    for (int u = 0; u < 2; ++u) {
      o2[u][t] = __builtin_amdgcn_mfma_f32_16x16x32_f16(G0[u].v, w0, o2[u][t], 0, 0, 0);
      o2[u][t] = __builtin_amdgcn_mfma_f32_16x16x32_f16(G1[u].v, w1, o2[u][t], 0, 0, 0);
    }
  }

  RunCtx rc0 = run_ctx(dd0, lane, q);
#pragma unroll
  for (int t = 0; t < 4; ++t) emit_t(o2[0][t], dd0, rc0, lane, m, t, xnew);
  RunCtx rc1 = run_ctx(dd1, lane, q);
#pragma unroll
  for (int t = 0; t < 4; ++t) emit_t(o2[1][t], dd1, rc1, lane, m, t, xnew);
}

// ---------------- fused fy + fx (t=1,2): 2 independent 16-edge tiles per wave ----------------
__global__ __launch_bounds__(256) void k_fyfx(
    const _Float16* __restrict__ xh, _Float16* __restrict__ y,
    const int* __restrict__ src, const int* __restrict__ dst,
    const _Float16* __restrict__ yB1, const float* __restrict__ yb1,
    const _Float16* __restrict__ yB2, const float* __restrict__ yb2,
    const _Float16* __restrict__ xB1, const float* __restrict__ xb1,
    const _Float16* __restrict__ xB2, const float* __restrict__ xb2,
    float* __restrict__ xnew, int E, int storeY) {
  __shared__ float hbuf[8][16 * 64];
  const int lane = threadIdx.x & 63;
  const int wv = threadIdx.x >> 6;
  const int m = lane & 15, q = lane >> 4;
  const int b0e = blockIdx.x * 128 + wv * 16;
  float* hb0 = hbuf[wv];
  float* hbx = hbuf[4 + wv];

  int em0 = b0e + m;       if (em0 >= E) em0 = E - 1;
  int em1 = b0e + 64 + m;  if (em1 >= E) em1 = E - 1;
  const int si0 = src[em0], di0 = dst[em0];
  const int si1 = src[em1], di1 = dst[em1];
  const bool live0 = (b0e + m) < E;
  const bool live1 = (b0e + 64 + m) < E;

  U8h Xs0[2], Xs1[2], Xd0[2], Xd1[2], Ho0[2], Ho1[2];
  {
    const _Float16* ps = xh + (size_t)si0 * 64 + q * 8;
    const _Float16* pd = xh + (size_t)di0 * 64 + q * 8;
    Xs0[0].v = *(const f16x8*)ps;  Xs1[0].v = *(const f16x8*)(ps + 32);
    Xd0[0].v = *(const f16x8*)pd;  Xd1[0].v = *(const f16x8*)(pd + 32);
  }
  {
    const _Float16* ps = xh + (size_t)si1 * 64 + q * 8;
    const _Float16* pd = xh + (size_t)di1 * 64 + q * 8;
    Xs0[1].v = *(const f16x8*)ps;  Xs1[1].v = *(const f16x8*)(ps + 32);
    Xd0[1].v = *(const f16x8*)pd;  Xd1[1].v = *(const f16x8*)(pd + 32);
  }
  {
    size_t yo0 = (size_t)em0 * 64 + q * 8;
    size_t yo1 = (size_t)em1 * 64 + q * 8;
    Ho0[0].v = *(const f16x8*)(y + yo0);  Ho1[0].v = *(const f16x8*)(y + yo0 + 32);
    Ho0[1].v = *(const f16x8*)(y + yo1);  Ho1[1].v = *(const f16x8*)(y + yo1 + 32);
  }

  // ---- fy layer 1 ----
  f32x4 acc[2][4];
#pragma unroll
  for (int t = 0; t < 4; ++t) {
    float bv = yb1[t * 16 + m];
    acc[0][t] = (f32x4){bv, bv, bv, bv};
    acc[1][t] = acc[0][t];
  }
#pragma unroll
  for (int t = 0; t < 4; ++t) {
    f16x8 w0 = *(const f16x8*)(yB1 + ((size_t)(0 * 4 + t) * 64 + lane) * 8);
    f16x8 w1 = *(const f16x8*)(yB1 + ((size_t)(1 * 4 + t) * 64 + lane) * 8);
    f16x8 w2 = *(const f16x8*)(yB1 + ((size_t)(2 * 4 + t) * 64 + lane) * 8);
    f16x8 w3 = *(const f16x8*)(yB1 + ((size_t)(3 * 4 + t) * 64 + lane) * 8);
#pragma unroll
    for (int u = 0; u < 2; ++u) {
      acc[u][t] = __builtin_amdgcn_mfma_f32_16x16x32_f16(Xd0[u].v, w0, acc[u][t], 0, 0, 0);
      acc[u][t] = __builtin_amdgcn_mfma_f32_16x16x32_f16(Xd1[u].v, w1, acc[u][t], 0, 0, 0);
      acc[u][t] = __builtin_amdgcn_mfma_f32_16x16x32_f16(Xs0[u].v, w2, acc[u][t], 0, 0, 0);
      acc[u][t] = __builtin_amdgcn_mfma_f32_16x16x32_f16(Xs1[u].v, w3, acc[u][t], 0, 0, 0);
    }
  }

#pragma unroll
  for (int t = 0; t < 4; ++t)
#pragma unroll
    for (int r = 0; r < 4; ++r) {
      hb0[swz(q * 4 + r, t * 16 + m)] = fmaxf(acc[0][t][r], 0.f);
      hbx[swz(q * 4 + r, t * 16 + m)] = fmaxf(acc[1][t][r], 0.f);
    }

  float fh0[16], fh1[16];
  load_row_swz(hb0, m, q, fh0);
  load_row_swz(hbx, m, q, fh1);
  U8h H0[2], H1[2];
  conv8_rne(fh0 + 0, H0[0]); conv8_rne(fh0 + 8, H1[0]);
  conv8_rne(fh1 + 0, H0[1]); conv8_rne(fh1 + 8, H1[1]);

  // ---- fy layer 2 ----
  f32x4 o[2][4];
#pragma unroll
  for (int t = 0; t < 4; ++t) {
    float bv = yb2[t * 16 + m];
    o[0][t] = (f32x4){bv, bv, bv, bv};
    o[1][t] = o[0][t];
  }
#pragma unroll
  for (int t = 0; t < 4; ++t) {
    f16x8 w0 = *(const f16x8*)(yB2 + ((size_t)(0 * 4 + t) * 64 + lane) * 8);
    f16x8 w1 = *(const f16x8*)(yB2 + ((size_t)(1 * 4 + t) * 64 + lane) * 8);
#pragma unroll
    for (int u = 0; u < 2; ++u) {
      o[u][t] = __builtin_amdgcn_mfma_f32_16x16x32_f16(H0[u].v, w0, o[u][t], 0, 0, 0);
      o[u][t] = __builtin_amdgcn_mfma_f32_16x16x32_f16(H1[u].v, w1, o[u][t], 0, 0, 0);
    }
  }

#pragma unroll
  for (int t = 0; t < 4; ++t)
#pragma unroll
    for (int r = 0; r < 4; ++r) {
      hb0[swz(q * 4 + r, t * 16 + m)] = o[0][t][r];
      hbx[swz(q * 4 + r, t * 16 + m)] = o[1][t][r];
    }

  float nv0[16], nv1[16];
  load_row_swz(hb0, m, q, nv0);
  load_row_swz(hbx, m, q, nv1);
#pragma unroll
  for (int i = 0; i < 8; ++i) {
    nv0[i]     = fmaxf((float)Ho0[0].s[i], nv0[i]);
    nv0[8 + i] = fmaxf((float)Ho1[0].s[i], nv0[8 + i]);
    nv1[i]     = fmaxf((float)Ho0[1].s[i], nv1[i]);
    nv1[8 + i] = fmaxf((float)Ho1[1].s[i], nv1[8 + i]);
  }
  U8h Yh0[2], Yh1[2];
  conv8_rne(nv0 + 0, Yh0[0]); conv8_rne(nv0 + 8, Yh1[0]);
  conv8_rne(nv1 + 0, Yh0[1]); conv8_rne(nv1 + 8, Yh1[1]);
  if (storeY) {
    if (live0) {
      size_t yo = (size_t)(b0e + m) * 64 + q * 8;
      *(f16x8*)(y + yo)      = Yh0[0].v;
      *(f16x8*)(y + yo + 32) = Yh1[0].v;
    }
    if (live1) {
      size_t yo = (size_t)(b0e + 64 + m) * 64 + q * 8;
      *(f16x8*)(y + yo)      = Yh0[1].v;
      *(f16x8*)(y + yo + 32) = Yh1[1].v;
    }
  }

  // ---- fx layer 1 ----
  f32x4 acc2[2][4];
#pragma unroll
  for (int t = 0; t < 4; ++t) {
    float bv = xb1[t * 16 + m];
    acc2[0][t] = (f32x4){bv, bv, bv, bv};
    acc2[1][t] = acc2[0][t];
  }
#pragma unroll
  for (int t = 0; t < 4; ++t) {
    f16x8 w0 = *(const f16x8*)(xB1 + ((size_t)(0 * 4 + t) * 64 + lane) * 8);
    f16x8 w1 = *(const f16x8*)(xB1 + ((size_t)(1 * 4 + t) * 64 + lane) * 8);
    f16x8 w2 = *(const f16x8*)(xB1 + ((size_t)(2 * 4 + t) * 64 + lane) * 8);
    f16x8 w3 = *(const f16x8*)(xB1 + ((size_t)(3 * 4 + t) * 64 + lane) * 8);
    f16x8 w4 = *(const f16x8*)(xB1 + ((size_t)(4 * 4 + t) * 64 + lane) * 8);
    f16x8 w5 = *(const f16x8*)(xB1 + ((size_t)(5 * 4 + t) * 64 + lane) * 8);
#pragma unroll
    for (int u = 0; u < 2; ++u) {
      acc2[u][t] = __builtin_amdgcn_mfma_f32_16x16x32_f16(Xs0[u].v, w0, acc2[u][t], 0, 0, 0);
      acc2[u][t] = __builtin_amdgcn_mfma_f32_16x16x32_f16(Xs1[u].v, w1, acc2[u][t], 0, 0, 0);
      acc2[u][t] = __builtin_amdgcn_mfma_f32_16x16x32_f16(Xd0[u].v, w2, acc2[u][t], 0, 0, 0);
      acc2[u][t] = __builtin_amdgcn_mfma_f32_16x16x32_f16(Xd1[u].v, w3, acc2[u][t], 0, 0, 0);
      acc2[u][t] = __builtin_amdgcn_mfma_f32_16x16x32_f16(Yh0[u].v, w4, acc2[u][t], 0, 0, 0);
      acc2[u][t] = __builtin_amdgcn_mfma_f32_16x16x32_f16(Yh1[u].v, w5, acc2[u][t], 0, 0, 0);
    }
  }

#pragma unroll
  for (int t = 0; t < 4; ++t)
#pragma unroll
    for (int r = 0; r < 4; ++r) {
      hb0[swz(q * 4 + r, t * 16 + m)] = fmaxf(acc2[0][t][r], 0.f);
      hbx[swz(q * 4 + r, t * 16 + m)] = fmaxf(acc2[1][t][r], 0.f);
    }

  float g0v[16], g1v[16];
  load_row_swz(hb0, m, q, g0v);
  load_row_swz(hbx, m, q, g1v);
  U8h G0[2], G1[2];
  conv8_rne(g0v + 0, G0[0]); conv8_rne(g0v + 8, G1[0]);
  conv8_rne(g1v + 0, G0[1]); conv8_rne(g1v + 8, G1[1]);

  // dst loads for emit (deferred to shorten register lifetimes)
  int dd0[4], dd1[4];
  {
    int e0 = b0e + q * 4;
#pragma unroll
    for (int r = 0; r < 4; ++r) {
      int e2 = e0 + r;
      dd0[r] = (e2 < E) ? dst[e2] : -1;
      int e3 = e2 + 64;
      dd1[r] = (e3 < E) ? dst[e3] : -1;
    }
  }

  // ---- fx layer 2 ----
  f32x4 o2[2][4];
#pragma unroll
  for (int t = 0; t < 4; ++t) {
    float bv = xb2[t * 16 + m];
    o2[0][t] = (f32x4){bv, bv, bv, bv};
    o2[1][t] = o2[0][t];
  }
#pragma unroll
  for (int t = 0; t < 4; ++t) {
    f16x8 w0 = *(const f16x8*)(xB2 + ((size_t)(0 * 4 + t) * 64 + lane) * 8);
    f16x8 w1 = *(const f16x8*)(xB2 + ((size_t)(1 * 4 + t) * 64 + lane) * 8);
#pragma unroll
    for (int u = 0; u < 2; ++u) {
      o2[u][t] = __builtin_amdgcn_mfma_f32_16x16x32_f16(G0[u].v, w0, o2[u][t], 0, 0, 0);
      o2[u][t] = __builtin_amdgcn_mfma_f32_16x16x32_f16(G1[u].v, w1, o2[u][t], 0, 0, 0);
    }
  }

  RunCtx rc0 = run_ctx(dd0, lane, q);
#pragma unroll
  for (int t = 0; t < 4; ++t) emit_t(o2[0][t], dd0, rc0, lane, m, t, xnew);
  RunCtx rc1 = run_ctx(dd1, lane, q);
#pragma unroll
  for (int t = 0; t < 4; ++t) emit_t(o2[1][t], dd1, rc1, lane, m, t, xnew);
}

// ---------------- feta (MFMA): out = w3 . relu(MLP2(x)) ----------------
__global__ __launch_bounds__(256) void k_feta2(
    const float* __restrict__ x,
    const _Float16* __restrict__ B1, const float* __restrict__ b1,
    const _Float16* __restrict__ B2, const float* __restrict__ b2,
    const float* __restrict__ w3, float* __restrict__ out, int N) {
  __shared__ float hbuf[4][16 * 64];
  const int lane = threadIdx.x & 63;
  const int wv = threadIdx.x >> 6;
  const int m = lane & 15, q = lane >> 4;
  const int base = blockIdx.x * 64 + wv * 16;
  int node = base + m; if (node >= N) node = N - 1;
  float fs[16];
  load_row(x + (size_t)node * 64 + q * 8, fs);
  U8h Ah[2], Al[2];
  dec8h(fs + 0, Ah[0], Al[0]);
  dec8h(fs + 8, Ah[1], Al[1]);

  f32x4 acc[4];
#pragma unroll
  for (int t = 0; t < 4; ++t) { float bv = b1[t * 16 + m]; acc[t] = (f32x4){bv, bv, bv, bv}; }
#pragma unroll
  for (int c = 0; c < 2; ++c) {
#pragma unroll
    for (int t = 0; t < 4; ++t) {
      f16x8 b = *(const f16x8*)(B1 + ((size_t)(c * 4 + t) * 64 + lane) * 8);
      acc[t] = __builtin_amdgcn_mfma_f32_16x16x32_f16(Ah[c].v, b, acc[t], 0, 0, 0);
      acc[t] = __builtin_amdgcn_mfma_f32_16x16x32_f16(Al[c].v, b, acc[t], 0, 0, 0);
    }
  }

  float* hb = hbuf[wv];
#pragma unroll
  for (int t = 0; t < 4; ++t)
#pragma unroll
    for (int r = 0; r < 4; ++r)
      hb[swz(q * 4 + r, t * 16 + m)] = fmaxf(acc[t][r], 0.f);

  float fh[16];
  load_row_swz(hb, m, q, fh);
  U8h A2h[2], A2l[2];
  dec8h(fh + 0, A2h[0], A2l[0]);
  dec8h(fh + 8, A2h[1], A2l[1]);

  f32x4 acc2[4];
#pragma unroll
  for (int t = 0; t < 4; ++t) { float bv = b2[t * 16 + m]; acc2[t] = (f32x4){bv, bv, bv, bv}; }
#pragma unroll
  for (int c = 0; c < 2; ++c) {
#pragma unroll
    for (int t = 0; t < 4; ++t) {
      f16x8 b = *(const f16x8*)(B2 + ((size_t)(c * 4 + t) * 64 + lane) * 8);
      acc2[t] = __builtin_amdgcn_mfma_f32_16x16x32_f16(A2h[c].v, b, acc2[t], 0, 0, 0);
      acc2[t] = __builtin_amdgcn_mfma_f32_16x16x32_f16(A2l[c].v, b, acc2[t], 0, 0, 0);
    }
  }

  float w3v[4];
#pragma unroll
  for (int t = 0; t < 4; ++t) w3v[t] = w3[t * 16 + m];
#pragma unroll
  for (int r = 0; r < 4; ++r) {
    float s = 0.f;
#pragma unroll
    for (int t = 0; t < 4; ++t) s += fmaxf(acc2[t][r], 0.f) * w3v[t];
    s += __shfl_xor(s, 1, 64);
    s += __shfl_xor(s, 2, 64);
    s += __shfl_xor(s, 4, 64);
    s += __shfl_xor(s, 8, 64);
    int row = base + q * 4 + r;
    if (m == 0 && row < N) out[row] = s;
  }
}

extern "C" void kernel_launch(void* const* d_in, const int* in_sizes, int n_in,
                              void* d_out, int out_size, void* d_ws, size_t ws_size,
                              hipStream_t stream) {
  const float* v      = (const float*)d_in[0];
  const float* labels = (const float*)d_in[1];
  const int*   ei     = (const int*)d_in[2];
  const float* hx_w1 = (const float*)d_in[4];
  const float* hx_b1 = (const float*)d_in[5];
  const float* hx_w2 = (const float*)d_in[6];
  const float* hx_b2 = (const float*)d_in[7];
  const float* hy_w1 = (const float*)d_in[8];
  const float* hy_b1 = (const float*)d_in[9];
  const float* hy_w2 = (const float*)d_in[10];
  const float* hy_b2 = (const float*)d_in[11];
  const float* fx_w1 = (const float*)d_in[12];
  const float* fx_b1 = (const float*)d_in[13];
  const float* fx_w2 = (const float*)d_in[14];
  const float* fx_b2 = (const float*)d_in[15];
  const float* fy_w1 = (const float*)d_in[16];
  const float* fy_b1 = (const float*)d_in[17];
  const float* fy_w2 = (const float*)d_in[18];
  const float* fy_b2 = (const float*)d_in[19];
  const float* feta_w1 = (const float*)d_in[20];
  const float* feta_b1 = (const float*)d_in[21];
  const float* feta_w2 = (const float*)d_in[22];
  const float* feta_b2 = (const float*)d_in[23];
  const float* feta_w3 = (const float*)d_in[24];

  int N = in_sizes[0] / 7;
  int E = in_sizes[2] / 2;
  const int* src = ei;
  const int* dst = ei + E;

  char* wsb = (char*)d_ws;
  float* goal = (float*)wsb;                                     // 16 f
  u64* goalkey = (u64*)(wsb + 64);
  float* b1p = (float*)(wsb + 96);                               // 64 f
  float* x = (float*)(wsb + 512);                                // N*64 f (in-place across rounds)
  _Float16* xh = (_Float16*)(x + (size_t)N * 64);                // N*64 f16 gather shadow
  _Float16* y = xh + (size_t)N * 64;                             // E*64 f16
  _Float16* wp = y + (size_t)E * 64;                             // 49152 f16
  float* vcp = (float*)(wp + 49152);                             // N*16 f
  int* deg = (int*)(vcp + (size_t)N * 16);                       // N
  int* cursor = deg + N;                                         // N
  int* srcp = cursor + N;                                        // E
  int* dstp = srcp + E;                                          // E
  int* bsum = dstp + E;                                          // 64

  _Float16* fxB1 = wp;          _Float16* fxB2 = wp + 12288;
  _Float16* fyB1 = wp + 16384;  _Float16* fyB2 = wp + 24576;
  _Float16* hyB1 = wp + 28672;  _Float16* hyB2 = wp + 30720;
  _Float16* hxB1 = wp + 34816;  _Float16* hxB2 = wp + 36864;
  _Float16* feB1 = wp + 40960;  _Float16* feB2 = wp + 45056;

  int SB = (N + 1023) / 1024;
  int NB = (N + 63) / 64;
  int EB2 = (E + 127) / 128;

  // prep weights + zero deg/goalkey (one kernel, no memset)
  k_prep<<<25, 256, 0, stream>>>(fx_w1, fx_w2, fy_w1, fy_w2, hy_w1, hy_w2,
                                 hx_w1, hx_w2, feta_w1, feta_w2, wp, goalkey, deg, N);
  k_vch<<<(N * 16 + 255) / 256, 256, 0, stream>>>(v, labels, vcp, N, dst, E, deg, goalkey);
  // scan1 + goal2b (independent, merged)
  k_scan1g<<<SB + 1, 256, 0, stream>>>(deg, N, SB, bsum, v, labels, goalkey,
                                       hx_w1, hx_b1, goal, b1p);
  // hx (needs b1p) + scan3 (needs bsum) merged
  k_hx2s<<<NB + SB, 256, 0, stream>>>(vcp, goal, hxB1, b1p, hxB2, hx_b2, x, xh, N,
                                      deg, bsum, cursor, NB);
  k_scatter<<<(E + 255) / 256, 256, 0, stream>>>(src, dst, E, cursor, srcp, dstp);

  // t=0: y0 = hy(vcp); x2 = max(x1, agg fx(x1,y0)) in place
  k_hyfx<<<EB2, 256, 0, stream>>>(vcp, xh, srcp, dstp,
                                  hyB1, hy_b1, hyB2, hy_b2,
                                  fxB1, fx_b1, fxB2, fx_b2, y, x, E);
  // t=1 (refresh fp16 shadow, atomics in place)
  k_ch<<<(N * 16 + 255) / 256, 256, 0, stream>>>((const float4*)x, xh, N * 16);
  k_fyfx<<<EB2, 256, 0, stream>>>(xh, y, srcp, dstp,
                                  fyB1, fy_b1, fyB2, fy_b2,
                                  fxB1, fx_b1, fxB2, fx_b2, x, E, 1);
  // t=2 (y dead after: skip its store)
  k_ch<<<(N * 16 + 255) / 256, 256, 0, stream>>>((const float4*)x, xh, N * 16);
  k_fyfx<<<EB2, 256, 0, stream>>>(xh, y, srcp, dstp,
                                  fyB1, fy_b1, fyB2, fy_b2,
                                  fxB1, fx_b1, fxB2, fx_b2, x, E, 0);

  k_feta2<<<NB, 256, 0, stream>>>(x, feB1, feta_b1, feB2, feta_b2, feta_w3,
                                  (float*)d_out, N);
}

// Round 3
// 327.240 us; speedup vs baseline: 1.0183x; 1.0183x over previous
//
#include <hip/hip_runtime.h>
#include <math.h>

typedef unsigned short u16;
typedef unsigned int u32;
typedef unsigned long long u64;
typedef __attribute__((ext_vector_type(8))) _Float16 f16x8;
typedef __attribute__((ext_vector_type(2))) _Float16 f16x2;
typedef __attribute__((ext_vector_type(4))) float f32x4;

union U8h { f16x8 v; f16x2 p[4]; u32 u[4]; _Float16 s[8]; };
union U4h { _Float16 s[4]; u64 u; };

__device__ __forceinline__ void atomicMaxF(float* addr, float val) {
  if (val >= 0.0f) {
    atomicMax((int*)addr, __float_as_int(val));
  } else {
    atomicMin((unsigned int*)addr, (unsigned int)__float_as_int(val));
  }
}

__device__ __forceinline__ f16x2 pk(float a, float b) {
  return __builtin_bit_cast(f16x2, __builtin_amdgcn_cvt_pkrtz(a, b));
}

// split 8 fp32 -> fp16 hi (RTZ) + lo (residual): hi+lo exact to ~2^-22
__device__ __forceinline__ void dec8h(const float* f, U8h& h, U8h& l) {
#pragma unroll
  for (int i = 0; i < 4; ++i) {
    float a = f[2 * i], b = f[2 * i + 1];
    f16x2 hp = pk(a, b);
    float ra = a - (float)hp[0];
    float rb = b - (float)hp[1];
    h.p[i] = hp;
    l.p[i] = pk(ra, rb);
  }
}

__device__ __forceinline__ void conv8_rne(const float* f, U8h& h) {
#pragma unroll
  for (int i = 0; i < 8; ++i) h.s[i] = (_Float16)f[i];
}

// lane's two 8-float chunks of a 64-float row (cols q*8.. and 32+q*8..)
// works for any row base pointer (global stride-64 or LDS stride-68 row)
__device__ __forceinline__ void load_row(const float* p, float* f) {
  *(float4*)(f + 0)  = *(const float4*)(p);
  *(float4*)(f + 4)  = *(const float4*)(p + 4);
  *(float4*)(f + 8)  = *(const float4*)(p + 32);
  *(float4*)(f + 12) = *(const float4*)(p + 36);
}

// ---- cross-q segmented-run merge for dst-sorted scatter-max ----
struct RunCtx { bool chain1, chain2, chain3, suppress; };

__device__ __forceinline__ RunCtx run_ctx(const int dd[4], int lane, int q) {
  bool allsame = (dd[0] == dd[1]) && (dd[1] == dd[2]) && (dd[2] == dd[3]);
  int nfd1 = __shfl(dd[0], lane + 16, 64);
  int nfd2 = __shfl(dd[0], lane + 32, 64);
  int nfd3 = __shfl(dd[0], lane + 48, 64);
  int as = allsame ? 1 : 0;
  int nas1 = __shfl(as, lane + 16, 64);
  int nas2 = __shfl(as, lane + 32, 64);
  int pld = __shfl(dd[3], lane - 16, 64);
  RunCtx c;
  c.chain1 = (q < 3) && (nfd1 == dd[3]);
  c.chain2 = c.chain1 && (nas1 != 0) && (q < 2) && (nfd2 == dd[3]);
  c.chain3 = c.chain2 && (nas2 != 0) && (q < 1) && (nfd3 == dd[3]);
  c.suppress = (q > 0) && (pld == dd[0]);
  return c;
}

__device__ __forceinline__ void emit_t(const f32x4 o, const int dd[4], const RunCtx c,
                                       int lane, int m, int t, float* __restrict__ xnew) {
  float fv = o[0];
  bool c01 = dd[1] == dd[0];
  fv = c01 ? fmaxf(fv, o[1]) : fv;
  bool c012 = c01 && (dd[2] == dd[1]);
  fv = c012 ? fmaxf(fv, o[2]) : fv;
  bool c0123 = c012 && (dd[3] == dd[2]);
  fv = c0123 ? fmaxf(fv, o[3]) : fv;
  float nfv1 = __shfl(fv, lane + 16, 64);
  float nfv2 = __shfl(fv, lane + 32, 64);
  float nfv3 = __shfl(fv, lane + 48, 64);
  float run = o[0];
  bool first = true;
#pragma unroll
  for (int r = 0; r < 4; ++r) {
    if (r > 0) run = (dd[r] == dd[r - 1]) ? fmaxf(run, o[r]) : o[r];
    bool end = (r == 3) || (dd[r + 1] != dd[r]);
    if (end) {
      float val = run;
      if (r == 3) {
        if (c.chain1) val = fmaxf(val, nfv1);
        if (c.chain2) val = fmaxf(val, nfv2);
        if (c.chain3) val = fmaxf(val, nfv3);
      }
      if (!(first && c.suppress) && dd[r] >= 0)
        atomicMaxF(&xnew[(size_t)dd[r] * 64 + t * 16 + m], val);
      first = false;
    }
  }
}

// ---------------- vcp build + degree histogram + goal argmax (fused) ----------------
__global__ __launch_bounds__(256) void k_vch(const float* __restrict__ v,
                                             const float* __restrict__ labels,
                                             float* __restrict__ vcp, int N,
                                             const int* __restrict__ dst, int E,
                                             int* __restrict__ deg, u64* __restrict__ key) {
  int tid = blockIdx.x * 256 + threadIdx.x;
  if (tid < N * 16) {
    int n = tid >> 4, c = tid & 15;
    float val = 0.f;
    if (c < 7) val = v[(size_t)n * 7 + c];
    else if (c == 7) val = labels[2 * (size_t)n];
    else if (c == 8) val = labels[2 * (size_t)n + 1];
    vcp[tid] = val;
  }
  if (tid < E) atomicAdd(&deg[dst[tid]], 1);
  if ((tid & ~63) < N) {
    float val = (tid < N) ? labels[2 * (size_t)tid + 1] : 0.0f;
    u64 k = ((u64)__float_as_uint(fmaxf(val, 0.0f)) << 32) | (u32)(~(u32)tid);
#pragma unroll
    for (int off = 32; off > 0; off >>= 1) {
      u64 o = __shfl_xor(k, off, 64);
      if (o > k) k = o;
    }
    if ((threadIdx.x & 63) == 0) atomicMax(key, k);
  }
}

// ---------------- weight prep (+ deg/goalkey zero init) ----------------
__global__ __launch_bounds__(256) void k_prep(const float* __restrict__ fxw1, const float* __restrict__ fxw2,
                                              const float* __restrict__ fyw1, const float* __restrict__ fyw2,
                                              const float* __restrict__ hyw1, const float* __restrict__ hyw2,
                                              const float* __restrict__ hxw1, const float* __restrict__ hxw2,
                                              const float* __restrict__ few1, const float* __restrict__ few2,
                                              _Float16* __restrict__ wp, u64* __restrict__ goalkey,
                                              int* __restrict__ deg, int N) {
  int tid = blockIdx.x * 256 + threadIdx.x;
  if (tid == 0) *goalkey = 0;
  for (int i = tid; i < N; i += gridDim.x * 256) deg[i] = 0;
  _Float16* fxB1 = wp;           // 12288
  _Float16* fxB2 = wp + 12288;   // 4096
  _Float16* fyB1 = wp + 16384;   // 8192
  _Float16* fyB2 = wp + 24576;   // 4096
  _Float16* hyB1 = wp + 28672;   // 2048
  _Float16* hyB2 = wp + 30720;   // 4096
  _Float16* hxB1 = wp + 34816;   // 2048
  _Float16* hxB2 = wp + 36864;   // 4096
  _Float16* feB1 = wp + 40960;   // 4096
  _Float16* feB2 = wp + 45056;   // 4096
  int which, id;
  _Float16* oh;
  if (tid < 1536)      { which = 0; id = tid;        oh = fxB1; }
  else if (tid < 2048) { which = 1; id = tid - 1536; oh = fxB2; }
  else if (tid < 3072) { which = 2; id = tid - 2048; oh = fyB1; }
  else if (tid < 3584) { which = 3; id = tid - 3072; oh = fyB2; }
  else if (tid < 3840) { which = 4; id = tid - 3584; oh = hyB1; }
  else if (tid < 4352) { which = 5; id = tid - 3840; oh = hyB2; }
  else if (tid < 4608) { which = 6; id = tid - 4352; oh = hxB1; }
  else if (tid < 5120) { which = 7; id = tid - 4608; oh = hxB2; }
  else if (tid < 5632) { which = 8; id = tid - 5120; oh = feB1; }
  else if (tid < 6144) { which = 9; id = tid - 5632; oh = feB2; }
  else return;
  int lane = id & 63;
  int q = lane >> 4, col = lane & 15;
  int c = id >> 8, t = (id >> 6) & 3;
#pragma unroll
  for (int j = 0; j < 8; ++j) {
    int k = c * 32 + q * 8 + j;
    int n = t * 16 + col;
    float w;
    if (which == 0) {
      w = (k < 64)  ? fxw1[k * 64 + n] + fxw1[(k + 64) * 64 + n]
        : (k < 128) ? fxw1[(k + 64) * 64 + n] - fxw1[(k - 64) * 64 + n]
                    : fxw1[(k + 64) * 64 + n];
    } else if (which == 1) {
      w = fxw2[k * 64 + n];
    } else if (which == 2) {
      w = (k < 64) ? fyw1[k * 64 + n] + fyw1[(k + 64) * 64 + n]
                   : fyw1[(k + 64) * 64 + n] - fyw1[(k - 64) * 64 + n];
    } else if (which == 3) {
      w = fyw2[k * 64 + n];
    } else if (which == 4) {
      if (k <= 8)                  w = hyw1[k * 64 + n] + hyw1[(k + 9) * 64 + n];
      else if (k >= 16 && k <= 24) w = hyw1[(k + 2) * 64 + n] - hyw1[(k - 16) * 64 + n];
      else                         w = 0.f;
    } else if (which == 5) {
      w = hyw2[k * 64 + n];
    } else if (which == 6) {
      w = (k < 9) ? hxw1[k * 64 + n] : (k < 27) ? hxw1[(k + 9) * 64 + n] : 0.f;
    } else if (which == 7) {
      w = hxw2[k * 64 + n];
    } else if (which == 8) {
      w = few1[k * 64 + n];
    } else {
      w = few2[k * 64 + n];
    }
    oh[id * 8 + j] = (_Float16)w;
  }
}

// ---------------- scan1 + goal2b merged (both depend only on k_vch) ----------------
__global__ __launch_bounds__(256) void k_scan1g(const int* __restrict__ deg, int N, int SB,
                                                int* __restrict__ bsum,
                                                const float* __restrict__ v,
                                                const float* __restrict__ labels,
                                                const u64* __restrict__ key,
                                                const float* __restrict__ hxw1,
                                                const float* __restrict__ hxb1,
                                                float* __restrict__ goal, float* __restrict__ b1p) {
  int b = blockIdx.x;
  if (b >= SB) {
    __shared__ float g[9];
    int gi = (int)(~(u32)(*key));
    int c = threadIdx.x;
    if (c < 9) {
      float gv = (c < 7) ? v[7 * (size_t)gi + c] : labels[2 * (size_t)gi + (c - 7)];
      g[c] = gv;
      goal[c] = gv;
    }
    __syncthreads();
    if (c < 64) {
      float s = hxb1[c];
#pragma unroll
      for (int k = 0; k < 9; ++k) s += g[k] * hxw1[(9 + k) * 64 + c];
      b1p[c] = s;
    }
    return;
  }
  __shared__ int red[256];
  int s = 0;
  for (int i = threadIdx.x; i < 1024; i += 256) {
    int idx = b * 1024 + i;
    s += (idx < N) ? deg[idx] : 0;
  }
  red[threadIdx.x] = s; __syncthreads();
  for (int st = 128; st > 0; st >>= 1) {
    if (threadIdx.x < st) red[threadIdx.x] += red[threadIdx.x + st];
    __syncthreads();
  }
  if (threadIdx.x == 0) bsum[b] = red[0];
}

// ---------------- hx (MFMA) + scan3 merged ----------------
__global__ __launch_bounds__(256) void k_hx2s(
    const float* __restrict__ vcp, const float* __restrict__ goal,
    const _Float16* __restrict__ B1, const float* __restrict__ b1p,
    const _Float16* __restrict__ B2, const float* __restrict__ b2,
    float* __restrict__ xout, _Float16* __restrict__ xh, int N,
    const int* __restrict__ deg, const int* __restrict__ bsum, int* __restrict__ cursor, int NB) {
  if ((int)blockIdx.x >= NB) {
    // ---- scan3 ----
    __shared__ int lsum[256];
    __shared__ int bofs;
    int b = blockIdx.x - NB;
    int tid = threadIdx.x;
    if (tid == 0) {
      int a = 0;
      for (int i = 0; i < b; ++i) a += bsum[i];
      bofs = a;
    }
    int base_i = b * 1024 + tid * 4;
    int loc[4]; int s = 0;
#pragma unroll
    for (int j = 0; j < 4; ++j) {
      int vv = (base_i + j < N) ? deg[base_i + j] : 0;
      loc[j] = s; s += vv;
    }
    lsum[tid] = s; __syncthreads();
    for (int st = 1; st < 256; st <<= 1) {
      int add = (tid >= st) ? lsum[tid - st] : 0;
      __syncthreads();
      lsum[tid] += add;
      __syncthreads();
    }
    int toff = bofs + lsum[tid] - s;
#pragma unroll
    for (int j = 0; j < 4; ++j) {
      if (base_i + j < N) cursor[base_i + j] = toff + loc[j];
    }
    return;
  }
  // ---- hx ----
  __shared__ float hbuf[4][16 * 68];
  const int lane = threadIdx.x & 63;
  const int wv = threadIdx.x >> 6;
  const int m = lane & 15, q = lane >> 4;
  const int base = blockIdx.x * 64 + wv * 16;
  int node = base + m; if (node >= N) node = N - 1;
  float vc[12];
  *(float4*)(vc + 0) = *(const float4*)(vcp + (size_t)node * 16);
  *(float4*)(vc + 4) = *(const float4*)(vcp + (size_t)node * 16 + 4);
  *(float4*)(vc + 8) = *(const float4*)(vcp + (size_t)node * 16 + 8);
  float gl[9];
#pragma unroll
  for (int i = 0; i < 9; ++i) gl[i] = goal[i];
  float f[8];
#pragma unroll
  for (int j = 0; j < 8; ++j) {
    int idx = q * 8 + j;
    float val = 0.f;
    if (idx < 9) val = vc[idx];
    else if (idx < 18) val = vc[idx - 9] - gl[idx - 9];
    else if (idx < 27) { float dv = vc[idx - 18] - gl[idx - 18]; val = dv * dv; }
    f[j] = val;
  }
  U8h Ah, Al;
  dec8h(f, Ah, Al);

  f32x4 acc[4];
#pragma unroll
  for (int t = 0; t < 4; ++t) { float bv = b1p[t * 16 + m]; acc[t] = (f32x4){bv, bv, bv, bv}; }
#pragma unroll
  for (int t = 0; t < 4; ++t) {
    f16x8 b = *(const f16x8*)(B1 + ((size_t)t * 64 + lane) * 8);
    acc[t] = __builtin_amdgcn_mfma_f32_16x16x32_f16(Ah.v, b, acc[t], 0, 0, 0);
    acc[t] = __builtin_amdgcn_mfma_f32_16x16x32_f16(Al.v, b, acc[t], 0, 0, 0);
  }

  float* hb = hbuf[wv];
#pragma unroll
  for (int t = 0; t < 4; ++t)
#pragma unroll
    for (int r = 0; r < 4; ++r)
      hb[(q * 4 + r) * 68 + t * 16 + m] = fmaxf(acc[t][r], 0.f);

  float fh[16];
  load_row(hb + m * 68 + q * 8, fh);
  U8h A2h[2], A2l[2];
  dec8h(fh + 0, A2h[0], A2l[0]);
  dec8h(fh + 8, A2h[1], A2l[1]);

  f32x4 acc2[4];
#pragma unroll
  for (int t = 0; t < 4; ++t) { float bv = b2[t * 16 + m]; acc2[t] = (f32x4){bv, bv, bv, bv}; }
#pragma unroll
  for (int c = 0; c < 2; ++c) {
#pragma unroll
    for (int t = 0; t < 4; ++t) {
      f16x8 b = *(const f16x8*)(B2 + ((size_t)(c * 4 + t) * 64 + lane) * 8);
      acc2[t] = __builtin_amdgcn_mfma_f32_16x16x32_f16(A2h[c].v, b, acc2[t], 0, 0, 0);
      acc2[t] = __builtin_amdgcn_mfma_f32_16x16x32_f16(A2l[c].v, b, acc2[t], 0, 0, 0);
    }
  }

#pragma unroll
  for (int t = 0; t < 4; ++t)
#pragma unroll
    for (int r = 0; r < 4; ++r)
      hb[(q * 4 + r) * 68 + t * 16 + m] = acc2[t][r];

  int row = base + m;
  if (row < N) {
    float ov[16];
    const float* orow = hb + m * 68 + q * 16;
    *(float4*)(ov + 0)  = *(const float4*)(orow);
    *(float4*)(ov + 4)  = *(const float4*)(orow + 4);
    *(float4*)(ov + 8)  = *(const float4*)(orow + 8);
    *(float4*)(ov + 12) = *(const float4*)(orow + 12);
    float* p1 = xout + (size_t)row * 64 + q * 16;
#pragma unroll
    for (int i = 0; i < 4; ++i) {
      *(float4*)(p1 + i * 4) = *(const float4*)(ov + i * 4);
    }
    U8h X0, X1;
    conv8_rne(ov + 0, X0);
    conv8_rne(ov + 8, X1);
    *(f16x8*)(xh + (size_t)row * 64 + q * 16)     = X0.v;
    *(f16x8*)(xh + (size_t)row * 64 + q * 16 + 8) = X1.v;
  }
}

__global__ __launch_bounds__(256) void k_scatter(const int* __restrict__ src,
                                                 const int* __restrict__ dst, int E,
                                                 int* __restrict__ cursor,
                                                 int* __restrict__ srcp, int* __restrict__ dstp) {
  int e = blockIdx.x * 256 + threadIdx.x;
  if (e < E) {
    int d = dst[e];
    int pos = atomicAdd(&cursor[d], 1);
    srcp[pos] = src[e];
    dstp[pos] = d;
  }
}

// ---------------- convert: fp16 gather shadow from fp32 x (in-place atomics; no copy) ----------------
__global__ __launch_bounds__(256) void k_ch(const float4* __restrict__ s,
                                            _Float16* __restrict__ h16, int n4) {
  int i = blockIdx.x * 256 + threadIdx.x;
  if (i < n4) {
    float4 v = s[i];
    U4h o;
    o.s[0] = (_Float16)v.x; o.s[1] = (_Float16)v.y;
    o.s[2] = (_Float16)v.z; o.s[3] = (_Float16)v.w;
    *(u64*)(h16 + (size_t)i * 4) = o.u;
  }
}

// ---------------- fused hy + fx (t=0): 2 independent 16-edge tiles per wave ----------------
__global__ __launch_bounds__(256) void k_hyfx(
    const float* __restrict__ vcp, const _Float16* __restrict__ xh,
    const int* __restrict__ src, const int* __restrict__ dst,
    const _Float16* __restrict__ hB1, const float* __restrict__ hb1,
    const _Float16* __restrict__ hB2, const float* __restrict__ hb2,
    const _Float16* __restrict__ xB1, const float* __restrict__ xb1,
    const _Float16* __restrict__ xB2, const float* __restrict__ xb2,
    _Float16* __restrict__ y, float* __restrict__ xnew, int E) {
  __shared__ float hbuf[8][16 * 68];
  const int lane = threadIdx.x & 63;
  const int wv = threadIdx.x >> 6;
  const int m = lane & 15, q = lane >> 4;
  const int b0e = blockIdx.x * 128 + wv * 16;
  float* hb0 = hbuf[wv];
  float* hbx = hbuf[4 + wv];

  int em0 = b0e + m;       if (em0 >= E) em0 = E - 1;
  int em1 = b0e + 64 + m;  if (em1 >= E) em1 = E - 1;
  const int si0 = src[em0], di0 = dst[em0];
  const int si1 = src[em1], di1 = dst[em1];
  const bool live0 = (b0e + m) < E;
  const bool live1 = (b0e + 64 + m) < E;

  U8h Xs0[2], Xs1[2], Xd0[2], Xd1[2];
  {
    const _Float16* ps = xh + (size_t)si0 * 64 + q * 8;
    const _Float16* pd = xh + (size_t)di0 * 64 + q * 8;
    Xs0[0].v = *(const f16x8*)ps;  Xs1[0].v = *(const f16x8*)(ps + 32);
    Xd0[0].v = *(const f16x8*)pd;  Xd1[0].v = *(const f16x8*)(pd + 32);
  }
  {
    const _Float16* ps = xh + (size_t)si1 * 64 + q * 8;
    const _Float16* pd = xh + (size_t)di1 * 64 + q * 8;
    Xs0[1].v = *(const f16x8*)ps;  Xs1[1].v = *(const f16x8*)(ps + 32);
    Xd0[1].v = *(const f16x8*)pd;  Xd1[1].v = *(const f16x8*)(pd + 32);
  }

  // hy A inputs (vcp of di for q<2, si for q>=2)
  U8h Ah[2], Al[2];
  {
    const int n0 = (q < 2) ? di0 : si0;
    const float* p = vcp + (size_t)n0 * 16 + (q & 1) * 8;
    float f[8];
    *(float4*)(f + 0) = *(const float4*)(p);
    *(float4*)(f + 4) = *(const float4*)(p + 4);
    dec8h(f, Ah[0], Al[0]);
  }
  {
    const int n1 = (q < 2) ? di1 : si1;
    const float* p = vcp + (size_t)n1 * 16 + (q & 1) * 8;
    float f[8];
    *(float4*)(f + 0) = *(const float4*)(p);
    *(float4*)(f + 4) = *(const float4*)(p + 4);
    dec8h(f, Ah[1], Al[1]);
  }

  // ---- hy layer 1 ----
  f32x4 acc[2][4];
#pragma unroll
  for (int t = 0; t < 4; ++t) {
    float bv = hb1[t * 16 + m];
    acc[0][t] = (f32x4){bv, bv, bv, bv};
    acc[1][t] = acc[0][t];
  }
#pragma unroll
  for (int t = 0; t < 4; ++t) {
    f16x8 w = *(const f16x8*)(hB1 + ((size_t)t * 64 + lane) * 8);
#pragma unroll
    for (int u = 0; u < 2; ++u) {
      acc[u][t] = __builtin_amdgcn_mfma_f32_16x16x32_f16(Ah[u].v, w, acc[u][t], 0, 0, 0);
      acc[u][t] = __builtin_amdgcn_mfma_f32_16x16x32_f16(Al[u].v, w, acc[u][t], 0, 0, 0);
    }
  }

#pragma unroll
  for (int t = 0; t < 4; ++t)
#pragma unroll
    for (int r = 0; r < 4; ++r) {
      hb0[(q * 4 + r) * 68 + t * 16 + m] = fmaxf(acc[0][t][r], 0.f);
      hbx[(q * 4 + r) * 68 + t * 16 + m] = fmaxf(acc[1][t][r], 0.f);
    }

  float fh0[16], fh1[16];
  load_row(hb0 + m * 68 + q * 8, fh0);
  load_row(hbx + m * 68 + q * 8, fh1);
  U8h H0[2], H1[2];
  conv8_rne(fh0 + 0, H0[0]); conv8_rne(fh0 + 8, H1[0]);
  conv8_rne(fh1 + 0, H0[1]); conv8_rne(fh1 + 8, H1[1]);

  // ---- hy layer 2 ----
  f32x4 o[2][4];
#pragma unroll
  for (int t = 0; t < 4; ++t) {
    float bv = hb2[t * 16 + m];
    o[0][t] = (f32x4){bv, bv, bv, bv};
    o[1][t] = o[0][t];
  }
#pragma unroll
  for (int t = 0; t < 4; ++t) {
    f16x8 w0 = *(const f16x8*)(hB2 + ((size_t)(0 * 4 + t) * 64 + lane) * 8);
    f16x8 w1 = *(const f16x8*)(hB2 + ((size_t)(1 * 4 + t) * 64 + lane) * 8);
#pragma unroll
    for (int u = 0; u < 2; ++u) {
      o[u][t] = __builtin_amdgcn_mfma_f32_16x16x32_f16(H0[u].v, w0, o[u][t], 0, 0, 0);
      o[u][t] = __builtin_amdgcn_mfma_f32_16x16x32_f16(H1[u].v, w1, o[u][t], 0, 0, 0);
    }
  }

#pragma unroll
  for (int t = 0; t < 4; ++t)
#pragma unroll
    for (int r = 0; r < 4; ++r) {
      hb0[(q * 4 + r) * 68 + t * 16 + m] = o[0][t][r];
      hbx[(q * 4 + r) * 68 + t * 16 + m] = o[1][t][r];
    }

  float nv0[16], nv1[16];
  load_row(hb0 + m * 68 + q * 8, nv0);
  load_row(hbx + m * 68 + q * 8, nv1);
  U8h Yh0[2], Yh1[2];
  conv8_rne(nv0 + 0, Yh0[0]); conv8_rne(nv0 + 8, Yh1[0]);
  conv8_rne(nv1 + 0, Yh0[1]); conv8_rne(nv1 + 8, Yh1[1]);
  if (live0) {
    size_t yo = (size_t)(b0e + m) * 64 + q * 8;
    *(f16x8*)(y + yo)      = Yh0[0].v;
    *(f16x8*)(y + yo + 32) = Yh1[0].v;
  }
  if (live1) {
    size_t yo = (size_t)(b0e + 64 + m) * 64 + q * 8;
    *(f16x8*)(y + yo)      = Yh0[1].v;
    *(f16x8*)(y + yo + 32) = Yh1[1].v;
  }

  // ---- fx layer 1 ----
  f32x4 acc2[2][4];
#pragma unroll
  for (int t = 0; t < 4; ++t) {
    float bv = xb1[t * 16 + m];
    acc2[0][t] = (f32x4){bv, bv, bv, bv};
    acc2[1][t] = acc2[0][t];
  }
#pragma unroll
  for (int t = 0; t < 4; ++t) {
    f16x8 w0 = *(const f16x8*)(xB1 + ((size_t)(0 * 4 + t) * 64 + lane) * 8);
    f16x8 w1 = *(const f16x8*)(xB1 + ((size_t)(1 * 4 + t) * 64 + lane) * 8);
    f16x8 w2 = *(const f16x8*)(xB1 + ((size_t)(2 * 4 + t) * 64 + lane) * 8);
    f16x8 w3 = *(const f16x8*)(xB1 + ((size_t)(3 * 4 + t) * 64 + lane) * 8);
    f16x8 w4 = *(const f16x8*)(xB1 + ((size_t)(4 * 4 + t) * 64 + lane) * 8);
    f16x8 w5 = *(const f16x8*)(xB1 + ((size_t)(5 * 4 + t) * 64 + lane) * 8);
#pragma unroll
    for (int u = 0; u < 2; ++u) {
      acc2[u][t] = __builtin_amdgcn_mfma_f32_16x16x32_f16(Xs0[u].v, w0, acc2[u][t], 0, 0, 0);
      acc2[u][t] = __builtin_amdgcn_mfma_f32_16x16x32_f16(Xs1[u].v, w1, acc2[u][t], 0, 0, 0);
      acc2[u][t] = __builtin_amdgcn_mfma_f32_16x16x32_f16(Xd0[u].v, w2, acc2[u][t], 0, 0, 0);
      acc2[u][t] = __builtin_amdgcn_mfma_f32_16x16x32_f16(Xd1[u].v, w3, acc2[u][t], 0, 0, 0);
      acc2[u][t] = __builtin_amdgcn_mfma_f32_16x16x32_f16(Yh0[u].v, w4, acc2[u][t], 0, 0, 0);
      acc2[u][t] = __builtin_amdgcn_mfma_f32_16x16x32_f16(Yh1[u].v, w5, acc2[u][t], 0, 0, 0);
    }
  }

#pragma unroll
  for (int t = 0; t < 4; ++t)
#pragma unroll
    for (int r = 0; r < 4; ++r) {
      hb0[(q * 4 + r) * 68 + t * 16 + m] = fmaxf(acc2[0][t][r], 0.f);
      hbx[(q * 4 + r) * 68 + t * 16 + m] = fmaxf(acc2[1][t][r], 0.f);
    }

  float g0v[16], g1v[16];
  load_row(hb0 + m * 68 + q * 8, g0v);
  load_row(hbx + m * 68 + q * 8, g1v);
  U8h G0[2], G1[2];
  conv8_rne(g0v + 0, G0[0]); conv8_rne(g0v + 8, G1[0]);
  conv8_rne(g1v + 0, G0[1]); conv8_rne(g1v + 8, G1[1]);

  // dst loads for emit (deferred)
  int dd0[4], dd1[4];
  {
    int e0 = b0e + q * 4;
#pragma unroll
    for (int r = 0; r < 4; ++r) {
      int e2 = e0 + r;
      dd0[r] = (e2 < E) ? dst[e2] : -1;
      int e3 = e2 + 64;
      dd1[r] = (e3 < E) ? dst[e3] : -1;
    }
  }

  // ---- fx layer 2 ----
  f32x4 o2[2][4];
#pragma unroll
  for (int t = 0; t < 4; ++t) {
    float bv = xb2[t * 16 + m];
    o2[0][t] = (f32x4){bv, bv, bv, bv};
    o2[1][t] = o2[0][t];
  }
#pragma unroll
  for (int t = 0; t < 4; ++t) {
    f16x8 w0 = *(const f16x8*)(xB2 + ((size_t)(0 * 4 + t) * 64 + lane) * 8);
    f16x8 w1 = *(const f16x8*)(xB2 + ((size_t)(1 * 4 + t) * 64 + lane) * 8);
#pragma unroll
    for (int u = 0; u < 2; ++u) {
      o2[u][t] = __builtin_amdgcn_mfma_f32_16x16x32_f16(G0[u].v, w0, o2[u][t], 0, 0, 0);
      o2[u][t] = __builtin_amdgcn_mfma_f32_16x16x32_f16(G1[u].v, w1, o2[u][t], 0, 0, 0);
    }
  }

  RunCtx rc0 = run_ctx(dd0, lane, q);
#pragma unroll
  for (int t = 0; t < 4; ++t) emit_t(o2[0][t], dd0, rc0, lane, m, t, xnew);
  RunCtx rc1 = run_ctx(dd1, lane, q);
#pragma unroll
  for (int t = 0; t < 4; ++t) emit_t(o2[1][t], dd1, rc1, lane, m, t, xnew);
}

// ---------------- fused fy + fx (t=1,2): 2 independent 16-edge tiles per wave ----------------
__global__ __launch_bounds__(256) void k_fyfx(
    const _Float16* __restrict__ xh, _Float16* __restrict__ y,
    const int* __restrict__ src, const int* __restrict__ dst,
    const _Float16* __restrict__ yB1, const float* __restrict__ yb1,
    const _Float16* __restrict__ yB2, const float* __restrict__ yb2,
    const _Float16* __restrict__ xB1, const float* __restrict__ xb1,
    const _Float16* __restrict__ xB2, const float* __restrict__ xb2,
    float* __restrict__ xnew, int E, int storeY) {
  __shared__ float hbuf[8][16 * 68];
  const int lane = threadIdx.x & 63;
  const int wv = threadIdx.x >> 6;
  const int m = lane & 15, q = lane >> 4;
  const int b0e = blockIdx.x * 128 + wv * 16;
  float* hb0 = hbuf[wv];
  float* hbx = hbuf[4 + wv];

  int em0 = b0e + m;       if (em0 >= E) em0 = E - 1;
  int em1 = b0e + 64 + m;  if (em1 >= E) em1 = E - 1;
  const int si0 = src[em0], di0 = dst[em0];
  const int si1 = src[em1], di1 = dst[em1];
  const bool live0 = (b0e + m) < E;
  const bool live1 = (b0e + 64 + m) < E;

  U8h Xs0[2], Xs1[2], Xd0[2], Xd1[2], Ho0[2], Ho1[2];
  {
    const _Float16* ps = xh + (size_t)si0 * 64 + q * 8;
    const _Float16* pd = xh + (size_t)di0 * 64 + q * 8;
    Xs0[0].v = *(const f16x8*)ps;  Xs1[0].v = *(const f16x8*)(ps + 32);
    Xd0[0].v = *(const f16x8*)pd;  Xd1[0].v = *(const f16x8*)(pd + 32);
  }
  {
    const _Float16* ps = xh + (size_t)si1 * 64 + q * 8;
    const _Float16* pd = xh + (size_t)di1 * 64 + q * 8;
    Xs0[1].v = *(const f16x8*)ps;  Xs1[1].v = *(const f16x8*)(ps + 32);
    Xd0[1].v = *(const f16x8*)pd;  Xd1[1].v = *(const f16x8*)(pd + 32);
  }
  {
    size_t yo0 = (size_t)em0 * 64 + q * 8;
    size_t yo1 = (size_t)em1 * 64 + q * 8;
    Ho0[0].v = *(const f16x8*)(y + yo0);  Ho1[0].v = *(const f16x8*)(y + yo0 + 32);
    Ho0[1].v = *(const f16x8*)(y + yo1);  Ho1[1].v = *(const f16x8*)(y + yo1 + 32);
  }

  // ---- fy layer 1 ----
  f32x4 acc[2][4];
#pragma unroll
  for (int t = 0; t < 4; ++t) {
    float bv = yb1[t * 16 + m];
    acc[0][t] = (f32x4){bv, bv, bv, bv};
    acc[1][t] = acc[0][t];
  }
#pragma unroll
  for (int t = 0; t < 4; ++t) {
    f16x8 w0 = *(const f16x8*)(yB1 + ((size_t)(0 * 4 + t) * 64 + lane) * 8);
    f16x8 w1 = *(const f16x8*)(yB1 + ((size_t)(1 * 4 + t) * 64 + lane) * 8);
    f16x8 w2 = *(const f16x8*)(yB1 + ((size_t)(2 * 4 + t) * 64 + lane) * 8);
    f16x8 w3 = *(const f16x8*)(yB1 + ((size_t)(3 * 4 + t) * 64 + lane) * 8);
#pragma unroll
    for (int u = 0; u < 2; ++u) {
      acc[u][t] = __builtin_amdgcn_mfma_f32_16x16x32_f16(Xd0[u].v, w0, acc[u][t], 0, 0, 0);
      acc[u][t] = __builtin_amdgcn_mfma_f32_16x16x32_f16(Xd1[u].v, w1, acc[u][t], 0, 0, 0);
      acc[u][t] = __builtin_amdgcn_mfma_f32_16x16x32_f16(Xs0[u].v, w2, acc[u][t], 0, 0, 0);
      acc[u][t] = __builtin_amdgcn_mfma_f32_16x16x32_f16(Xs1[u].v, w3, acc[u][t], 0, 0, 0);
    }
  }

#pragma unroll
  for (int t = 0; t < 4; ++t)
#pragma unroll
    for (int r = 0; r < 4; ++r) {
      hb0[(q * 4 + r) * 68 + t * 16 + m] = fmaxf(acc[0][t][r], 0.f);
      hbx[(q * 4 + r) * 68 + t * 16 + m] = fmaxf(acc[1][t][r], 0.f);
    }

  float fh0[16], fh1[16];
  load_row(hb0 + m * 68 + q * 8, fh0);
  load_row(hbx + m * 68 + q * 8, fh1);
  U8h H0[2], H1[2];
  conv8_rne(fh0 + 0, H0[0]); conv8_rne(fh0 + 8, H1[0]);
  conv8_rne(fh1 + 0, H0[1]); conv8_rne(fh1 + 8, H1[1]);

  // ---- fy layer 2 ----
  f32x4 o[2][4];
#pragma unroll
  for (int t = 0; t < 4; ++t) {
    float bv = yb2[t * 16 + m];
    o[0][t] = (f32x4){bv, bv, bv, bv};
    o[1][t] = o[0][t];
  }
#pragma unroll
  for (int t = 0; t < 4; ++t) {
    f16x8 w0 = *(const f16x8*)(yB2 + ((size_t)(0 * 4 + t) * 64 + lane) * 8);
    f16x8 w1 = *(const f16x8*)(yB2 + ((size_t)(1 * 4 + t) * 64 + lane) * 8);
#pragma unroll
    for (int u = 0; u < 2; ++u) {
      o[u][t] = __builtin_amdgcn_mfma_f32_16x16x32_f16(H0[u].v, w0, o[u][t], 0, 0, 0);
      o[u][t] = __builtin_amdgcn_mfma_f32_16x16x32_f16(H1[u].v, w1, o[u][t], 0, 0, 0);
    }
  }

#pragma unroll
  for (int t = 0; t < 4; ++t)
#pragma unroll
    for (int r = 0; r < 4; ++r) {
      hb0[(q * 4 + r) * 68 + t * 16 + m] = o[0][t][r];
      hbx[(q * 4 + r) * 68 + t * 16 + m] = o[1][t][r];
    }

  float nv0[16], nv1[16];
  load_row(hb0 + m * 68 + q * 8, nv0);
  load_row(hbx + m * 68 + q * 8, nv1);
#pragma unroll
  for (int i = 0; i < 8; ++i) {
    nv0[i]     = fmaxf((float)Ho0[0].s[i], nv0[i]);
    nv0[8 + i] = fmaxf((float)Ho1[0].s[i], nv0[8 + i]);
    nv1[i]     = fmaxf((float)Ho0[1].s[i], nv1[i]);
    nv1[8 + i] = fmaxf((float)Ho1[1].s[i], nv1[8 + i]);
  }
  U8h Yh0[2], Yh1[2];
  conv8_rne(nv0 + 0, Yh0[0]); conv8_rne(nv0 + 8, Yh1[0]);
  conv8_rne(nv1 + 0, Yh0[1]); conv8_rne(nv1 + 8, Yh1[1]);
  if (storeY) {
    if (live0) {
      size_t yo = (size_t)(b0e + m) * 64 + q * 8;
      *(f16x8*)(y + yo)      = Yh0[0].v;
      *(f16x8*)(y + yo + 32) = Yh1[0].v;
    }
    if (live1) {
      size_t yo = (size_t)(b0e + 64 + m) * 64 + q * 8;
      *(f16x8*)(y + yo)      = Yh0[1].v;
      *(f16x8*)(y + yo + 32) = Yh1[1].v;
    }
  }

  // ---- fx layer 1 ----
  f32x4 acc2[2][4];
#pragma unroll
  for (int t = 0; t < 4; ++t) {
    float bv = xb1[t * 16 + m];
    acc2[0][t] = (f32x4){bv, bv, bv, bv};
    acc2[1][t] = acc2[0][t];
  }
#pragma unroll
  for (int t = 0; t < 4; ++t) {
    f16x8 w0 = *(const f16x8*)(xB1 + ((size_t)(0 * 4 + t) * 64 + lane) * 8);
    f16x8 w1 = *(const f16x8*)(xB1 + ((size_t)(1 * 4 + t) * 64 + lane) * 8);
    f16x8 w2 = *(const f16x8*)(xB1 + ((size_t)(2 * 4 + t) * 64 + lane) * 8);
    f16x8 w3 = *(const f16x8*)(xB1 + ((size_t)(3 * 4 + t) * 64 + lane) * 8);
    f16x8 w4 = *(const f16x8*)(xB1 + ((size_t)(4 * 4 + t) * 64 + lane) * 8);
    f16x8 w5 = *(const f16x8*)(xB1 + ((size_t)(5 * 4 + t) * 64 + lane) * 8);
#pragma unroll
    for (int u = 0; u < 2; ++u) {
      acc2[u][t] = __builtin_amdgcn_mfma_f32_16x16x32_f16(Xs0[u].v, w0, acc2[u][t], 0, 0, 0);
      acc2[u][t] = __builtin_amdgcn_mfma_f32_16x16x32_f16(Xs1[u].v, w1, acc2[u][t], 0, 0, 0);
      acc2[u][t] = __builtin_amdgcn_mfma_f32_16x16x32_f16(Xd0[u].v, w2, acc2[u][t], 0, 0, 0);
      acc2[u][t] = __builtin_amdgcn_mfma_f32_16x16x32_f16(Xd1[u].v, w3, acc2[u][t], 0, 0, 0);
      acc2[u][t] = __builtin_amdgcn_mfma_f32_16x16x32_f16(Yh0[u].v, w4, acc2[u][t], 0, 0, 0);
      acc2[u][t] = __builtin_amdgcn_mfma_f32_16x16x32_f16(Yh1[u].v, w5, acc2[u][t], 0, 0, 0);
    }
  }

#pragma unroll
  for (int t = 0; t < 4; ++t)
#pragma unroll
    for (int r = 0; r < 4; ++r) {
      hb0[(q * 4 + r) * 68 + t * 16 + m] = fmaxf(acc2[0][t][r], 0.f);
      hbx[(q * 4 + r) * 68 + t * 16 + m] = fmaxf(acc2[1][t][r], 0.f);
    }

  float g0v[16], g1v[16];
  load_row(hb0 + m * 68 + q * 8, g0v);
  load_row(hbx + m * 68 + q * 8, g1v);
  U8h G0[2], G1[2];
  conv8_rne(g0v + 0, G0[0]); conv8_rne(g0v + 8, G1[0]);
  conv8_rne(g1v + 0, G0[1]); conv8_rne(g1v + 8, G1[1]);

  // dst loads for emit (deferred to shorten register lifetimes)
  int dd0[4], dd1[4];
  {
    int e0 = b0e + q * 4;
#pragma unroll
    for (int r = 0; r < 4; ++r) {
      int e2 = e0 + r;
      dd0[r] = (e2 < E) ? dst[e2] : -1;
      int e3 = e2 + 64;
      dd1[r] = (e3 < E) ? dst[e3] : -1;
    }
  }

  // ---- fx layer 2 ----
  f32x4 o2[2][4];
#pragma unroll
  for (int t = 0; t < 4; ++t) {
    float bv = xb2[t * 16 + m];
    o2[0][t] = (f32x4){bv, bv, bv, bv};
    o2[1][t] = o2[0][t];
  }
#pragma unroll
  for (int t = 0; t < 4; ++t) {
    f16x8 w0 = *(const f16x8*)(xB2 + ((size_t)(0 * 4 + t) * 64 + lane) * 8);
    f16x8 w1 = *(const f16x8*)(xB2 + ((size_t)(1 * 4 + t) * 64 + lane) * 8);
#pragma unroll
    for (int u = 0; u < 2; ++u) {
      o2[u][t] = __builtin_amdgcn_mfma_f32_16x16x32_f16(G0[u].v, w0, o2[u][t], 0, 0, 0);
      o2[u][t] = __builtin_amdgcn_mfma_f32_16x16x32_f16(G1[u].v, w1, o2[u][t], 0, 0, 0);
    }
  }

  RunCtx rc0 = run_ctx(dd0, lane, q);
#pragma unroll
  for (int t = 0; t < 4; ++t) emit_t(o2[0][t], dd0, rc0, lane, m, t, xnew);
  RunCtx rc1 = run_ctx(dd1, lane, q);
#pragma unroll
  for (int t = 0; t < 4; ++t) emit_t(o2[1][t], dd1, rc1, lane, m, t, xnew);
}

// ---------------- feta (MFMA): out = w3 . relu(MLP2(x)) ----------------
__global__ __launch_bounds__(256) void k_feta2(
    const float* __restrict__ x,
    const _Float16* __restrict__ B1, const float* __restrict__ b1,
    const _Float16* __restrict__ B2, const float* __restrict__ b2,
    const float* __restrict__ w3, float* __restrict__ out, int N) {
  __shared__ float hbuf[4][16 * 68];
  const int lane = threadIdx.x & 63;
  const int wv = threadIdx.x >> 6;
  const int m = lane & 15, q = lane >> 4;
  const int base = blockIdx.x * 64 + wv * 16;
  int node = base + m; if (node >= N) node = N - 1;
  float fs[16];
  load_row(x + (size_t)node * 64 + q * 8, fs);
  U8h Ah[2], Al[2];
  dec8h(fs + 0, Ah[0], Al[0]);
  dec8h(fs + 8, Ah[1], Al[1]);

  f32x4 acc[4];
#pragma unroll
  for (int t = 0; t < 4; ++t) { float bv = b1[t * 16 + m]; acc[t] = (f32x4){bv, bv, bv, bv}; }
#pragma unroll
  for (int c = 0; c < 2; ++c) {
#pragma unroll
    for (int t = 0; t < 4; ++t) {
      f16x8 b = *(const f16x8*)(B1 + ((size_t)(c * 4 + t) * 64 + lane) * 8);
      acc[t] = __builtin_amdgcn_mfma_f32_16x16x32_f16(Ah[c].v, b, acc[t], 0, 0, 0);
      acc[t] = __builtin_amdgcn_mfma_f32_16x16x32_f16(Al[c].v, b, acc[t], 0, 0, 0);
    }
  }

  float* hb = hbuf[wv];
#pragma unroll
  for (int t = 0; t < 4; ++t)
#pragma unroll
    for (int r = 0; r < 4; ++r)
      hb[(q * 4 + r) * 68 + t * 16 + m] = fmaxf(acc[t][r], 0.f);

  float fh[16];
  load_row(hb + m * 68 + q * 8, fh);
  U8h A2h[2], A2l[2];
  dec8h(fh + 0, A2h[0], A2l[0]);
  dec8h(fh + 8, A2h[1], A2l[1]);

  f32x4 acc2[4];
#pragma unroll
  for (int t = 0; t < 4; ++t) { float bv = b2[t * 16 + m]; acc2[t] = (f32x4){bv, bv, bv, bv}; }
#pragma unroll
  for (int c = 0; c < 2; ++c) {
#pragma unroll
    for (int t = 0; t < 4; ++t) {
      f16x8 b = *(const f16x8*)(B2 + ((size_t)(c * 4 + t) * 64 + lane) * 8);
      acc2[t] = __builtin_amdgcn_mfma_f32_16x16x32_f16(A2h[c].v, b, acc2[t], 0, 0, 0);
      acc2[t] = __builtin_amdgcn_mfma_f32_16x16x32_f16(A2l[c].v, b, acc2[t], 0, 0, 0);
    }
  }

  float w3v[4];
#pragma unroll
  for (int t = 0; t < 4; ++t) w3v[t] = w3[t * 16 + m];
#pragma unroll
  for (int r = 0; r < 4; ++r) {
    float s = 0.f;
#pragma unroll
    for (int t = 0; t < 4; ++t) s += fmaxf(acc2[t][r], 0.f) * w3v[t];
    s += __shfl_xor(s, 1, 64);
    s += __shfl_xor(s, 2, 64);
    s += __shfl_xor(s, 4, 64);
    s += __shfl_xor(s, 8, 64);
    int row = base + q * 4 + r;
    if (m == 0 && row < N) out[row] = s;
  }
}

extern "C" void kernel_launch(void* const* d_in, const int* in_sizes, int n_in,
                              void* d_out, int out_size, void* d_ws, size_t ws_size,
                              hipStream_t stream) {
  const float* v      = (const float*)d_in[0];
  const float* labels = (const float*)d_in[1];
  const int*   ei     = (const int*)d_in[2];
  const float* hx_w1 = (const float*)d_in[4];
  const float* hx_b1 = (const float*)d_in[5];
  const float* hx_w2 = (const float*)d_in[6];
  const float* hx_b2 = (const float*)d_in[7];
  const float* hy_w1 = (const float*)d_in[8];
  const float* hy_b1 = (const float*)d_in[9];
  const float* hy_w2 = (const float*)d_in[10];
  const float* hy_b2 = (const float*)d_in[11];
  const float* fx_w1 = (const float*)d_in[12];
  const float* fx_b1 = (const float*)d_in[13];
  const float* fx_w2 = (const float*)d_in[14];
  const float* fx_b2 = (const float*)d_in[15];
  const float* fy_w1 = (const float*)d_in[16];
  const float* fy_b1 = (const float*)d_in[17];
  const float* fy_w2 = (const float*)d_in[18];
  const float* fy_b2 = (const float*)d_in[19];
  const float* feta_w1 = (const float*)d_in[20];
  const float* feta_b1 = (const float*)d_in[21];
  const float* feta_w2 = (const float*)d_in[22];
  const float* feta_b2 = (const float*)d_in[23];
  const float* feta_w3 = (const float*)d_in[24];

  int N = in_sizes[0] / 7;
  int E = in_sizes[2] / 2;
  const int* src = ei;
  const int* dst = ei + E;

  char* wsb = (char*)d_ws;
  float* goal = (float*)wsb;                                     // 16 f
  u64* goalkey = (u64*)(wsb + 64);
  float* b1p = (float*)(wsb + 96);                               // 64 f
  float* x = (float*)(wsb + 512);                                // N*64 f (in-place across rounds)
  _Float16* xh = (_Float16*)(x + (size_t)N * 64);                // N*64 f16 gather shadow
  _Float16* y = xh + (size_t)N * 64;                             // E*64 f16
  _Float16* wp = y + (size_t)E * 64;                             // 49152 f16
  float* vcp = (float*)(wp + 49152);                             // N*16 f
  int* deg = (int*)(vcp + (size_t)N * 16);                       // N
  int* cursor = deg + N;                                         // N
  int* srcp = cursor + N;                                        // E
  int* dstp = srcp + E;                                          // E
  int* bsum = dstp + E;                                          // 64

  _Float16* fxB1 = wp;          _Float16* fxB2 = wp + 12288;
  _Float16* fyB1 = wp + 16384;  _Float16* fyB2 = wp + 24576;
  _Float16* hyB1 = wp + 28672;  _Float16* hyB2 = wp + 30720;
  _Float16* hxB1 = wp + 34816;  _Float16* hxB2 = wp + 36864;
  _Float16* feB1 = wp + 40960;  _Float16* feB2 = wp + 45056;

  int SB = (N + 1023) / 1024;
  int NB = (N + 63) / 64;
  int EB2 = (E + 127) / 128;

  // prep weights + zero deg/goalkey (one kernel, no memset)
  k_prep<<<25, 256, 0, stream>>>(fx_w1, fx_w2, fy_w1, fy_w2, hy_w1, hy_w2,
                                 hx_w1, hx_w2, feta_w1, feta_w2, wp, goalkey, deg, N);
  k_vch<<<(N * 16 + 255) / 256, 256, 0, stream>>>(v, labels, vcp, N, dst, E, deg, goalkey);
  // scan1 + goal2b (independent, merged)
  k_scan1g<<<SB + 1, 256, 0, stream>>>(deg, N, SB, bsum, v, labels, goalkey,
                                       hx_w1, hx_b1, goal, b1p);
  // hx (needs b1p) + scan3 (needs bsum) merged
  k_hx2s<<<NB + SB, 256, 0, stream>>>(vcp, goal, hxB1, b1p, hxB2, hx_b2, x, xh, N,
                                      deg, bsum, cursor, NB);
  k_scatter<<<(E + 255) / 256, 256, 0, stream>>>(src, dst, E, cursor, srcp, dstp);

  // t=0: y0 = hy(vcp); x2 = max(x1, agg fx(x1,y0)) in place
  k_hyfx<<<EB2, 256, 0, stream>>>(vcp, xh, srcp, dstp,
                                  hyB1, hy_b1, hyB2, hy_b2,
                                  fxB1, fx_b1, fxB2, fx_b2, y, x, E);
  // t=1 (refresh fp16 shadow, atomics in place)
  k_ch<<<(N * 16 + 255) / 256, 256, 0, stream>>>((const float4*)x, xh, N * 16);
  k_fyfx<<<EB2, 256, 0, stream>>>(xh, y, srcp, dstp,
                                  fyB1, fy_b1, fyB2, fy_b2,
                                  fxB1, fx_b1, fxB2, fx_b2, x, E, 1);
  // t=2 (y dead after: skip its store)
  k_ch<<<(N * 16 + 255) / 256, 256, 0, stream>>>((const float4*)x, xh, N * 16);
  k_fyfx<<<EB2, 256, 0, stream>>>(xh, y, srcp, dstp,
                                  fyB1, fy_b1, fyB2, fy_b2,
                                  fxB1, fx_b1, fxB2, fx_b2, x, E, 0);

  k_feta2<<<NB, 256, 0, stream>>>(x, feB1, feta_b1, feB2, feta_b2, feta_w3,
                                  (float*)d_out, N);
}

// Round 4
// 320.066 us; speedup vs baseline: 1.0412x; 1.0224x over previous
//
#include <hip/hip_runtime.h>
#include <math.h>

typedef unsigned short u16;
typedef unsigned int u32;
typedef unsigned long long u64;
typedef __attribute__((ext_vector_type(8))) _Float16 f16x8;
typedef __attribute__((ext_vector_type(2))) _Float16 f16x2;
typedef __attribute__((ext_vector_type(4))) float f32x4;

union U8h { f16x8 v; f16x2 p[4]; u32 u[4]; _Float16 s[8]; };
union U4h { _Float16 s[4]; u64 u; };

__device__ __forceinline__ void atomicMaxF(float* addr, float val) {
  if (val >= 0.0f) {
    atomicMax((int*)addr, __float_as_int(val));
  } else {
    atomicMin((unsigned int*)addr, (unsigned int)__float_as_int(val));
  }
}

__device__ __forceinline__ f16x2 pk(float a, float b) {
  return __builtin_bit_cast(f16x2, __builtin_amdgcn_cvt_pkrtz(a, b));
}

// split 8 fp32 -> fp16 hi (RTZ) + lo (residual): hi+lo exact to ~2^-22
__device__ __forceinline__ void dec8h(const float* f, U8h& h, U8h& l) {
#pragma unroll
  for (int i = 0; i < 4; ++i) {
    float a = f[2 * i], b = f[2 * i + 1];
    f16x2 hp = pk(a, b);
    float ra = a - (float)hp[0];
    float rb = b - (float)hp[1];
    h.p[i] = hp;
    l.p[i] = pk(ra, rb);
  }
}

__device__ __forceinline__ void conv8_rne(const float* f, U8h& h) {
#pragma unroll
  for (int i = 0; i < 8; ++i) h.s[i] = (_Float16)f[i];
}

// elementwise fp16 max of two 8-vectors
__device__ __forceinline__ f16x8 hmax8(f16x8 a, f16x8 b) {
  f16x8 r;
#pragma unroll
  for (int i = 0; i < 8; ++i) r[i] = a[i] > b[i] ? a[i] : b[i];
  return r;
}

// lane's two 8-float chunks of a 64-float row (cols q*8.. and 32+q*8..)
// works for any row base pointer (global stride-64 or LDS stride-68 row)
__device__ __forceinline__ void load_row(const float* p, float* f) {
  *(float4*)(f + 0)  = *(const float4*)(p);
  *(float4*)(f + 4)  = *(const float4*)(p + 4);
  *(float4*)(f + 8)  = *(const float4*)(p + 32);
  *(float4*)(f + 12) = *(const float4*)(p + 36);
}

// ---- cross-q segmented-run merge for dst-sorted scatter-max ----
struct RunCtx { bool chain1, chain2, chain3, suppress; };

__device__ __forceinline__ RunCtx run_ctx(const int dd[4], int lane, int q) {
  bool allsame = (dd[0] == dd[1]) && (dd[1] == dd[2]) && (dd[2] == dd[3]);
  int nfd1 = __shfl(dd[0], lane + 16, 64);
  int nfd2 = __shfl(dd[0], lane + 32, 64);
  int nfd3 = __shfl(dd[0], lane + 48, 64);
  int as = allsame ? 1 : 0;
  int nas1 = __shfl(as, lane + 16, 64);
  int nas2 = __shfl(as, lane + 32, 64);
  int pld = __shfl(dd[3], lane - 16, 64);
  RunCtx c;
  c.chain1 = (q < 3) && (nfd1 == dd[3]);
  c.chain2 = c.chain1 && (nas1 != 0) && (q < 2) && (nfd2 == dd[3]);
  c.chain3 = c.chain2 && (nas2 != 0) && (q < 1) && (nfd3 == dd[3]);
  c.suppress = (q > 0) && (pld == dd[0]);
  return c;
}

__device__ __forceinline__ void emit_t(const f32x4 o, const int dd[4], const RunCtx c,
                                       int lane, int m, int t, float* __restrict__ xnew) {
  float fv = o[0];
  bool c01 = dd[1] == dd[0];
  fv = c01 ? fmaxf(fv, o[1]) : fv;
  bool c012 = c01 && (dd[2] == dd[1]);
  fv = c012 ? fmaxf(fv, o[2]) : fv;
  bool c0123 = c012 && (dd[3] == dd[2]);
  fv = c0123 ? fmaxf(fv, o[3]) : fv;
  float nfv1 = __shfl(fv, lane + 16, 64);
  float nfv2 = __shfl(fv, lane + 32, 64);
  float nfv3 = __shfl(fv, lane + 48, 64);
  float run = o[0];
  bool first = true;
#pragma unroll
  for (int r = 0; r < 4; ++r) {
    if (r > 0) run = (dd[r] == dd[r - 1]) ? fmaxf(run, o[r]) : o[r];
    bool end = (r == 3) || (dd[r + 1] != dd[r]);
    if (end) {
      float val = run;
      if (r == 3) {
        if (c.chain1) val = fmaxf(val, nfv1);
        if (c.chain2) val = fmaxf(val, nfv2);
        if (c.chain3) val = fmaxf(val, nfv3);
      }
      if (!(first && c.suppress) && dd[r] >= 0)
        atomicMaxF(&xnew[(size_t)dd[r] * 64 + t * 16 + m], val);
      first = false;
    }
  }
}

// ---------------- vcp build + degree histogram + goal argmax (fused) ----------------
__global__ __launch_bounds__(256) void k_vch(const float* __restrict__ v,
                                             const float* __restrict__ labels,
                                             float* __restrict__ vcp, int N,
                                             const int* __restrict__ dst, int E,
                                             int* __restrict__ deg, u64* __restrict__ key) {
  int tid = blockIdx.x * 256 + threadIdx.x;
  if (tid < N * 16) {
    int n = tid >> 4, c = tid & 15;
    float val = 0.f;
    if (c < 7) val = v[(size_t)n * 7 + c];
    else if (c == 7) val = labels[2 * (size_t)n];
    else if (c == 8) val = labels[2 * (size_t)n + 1];
    vcp[tid] = val;
  }
  if (tid < E) atomicAdd(&deg[dst[tid]], 1);
  if ((tid & ~63) < N) {
    float val = (tid < N) ? labels[2 * (size_t)tid + 1] : 0.0f;
    u64 k = ((u64)__float_as_uint(fmaxf(val, 0.0f)) << 32) | (u32)(~(u32)tid);
#pragma unroll
    for (int off = 32; off > 0; off >>= 1) {
      u64 o = __shfl_xor(k, off, 64);
      if (o > k) k = o;
    }
    if ((threadIdx.x & 63) == 0) atomicMax(key, k);
  }
}

// ---------------- weight prep (+ deg/goalkey zero init) ----------------
__global__ __launch_bounds__(256) void k_prep(const float* __restrict__ fxw1, const float* __restrict__ fxw2,
                                              const float* __restrict__ fyw1, const float* __restrict__ fyw2,
                                              const float* __restrict__ hyw1, const float* __restrict__ hyw2,
                                              const float* __restrict__ hxw1, const float* __restrict__ hxw2,
                                              const float* __restrict__ few1, const float* __restrict__ few2,
                                              _Float16* __restrict__ wp, u64* __restrict__ goalkey,
                                              int* __restrict__ deg, int N) {
  int tid = blockIdx.x * 256 + threadIdx.x;
  if (tid == 0) *goalkey = 0;
  for (int i = tid; i < N; i += gridDim.x * 256) deg[i] = 0;
  _Float16* fxB1 = wp;           // 12288
  _Float16* fxB2 = wp + 12288;   // 4096
  _Float16* fyB1 = wp + 16384;   // 8192
  _Float16* fyB2 = wp + 24576;   // 4096
  _Float16* hyB1 = wp + 28672;   // 2048
  _Float16* hyB2 = wp + 30720;   // 4096
  _Float16* hxB1 = wp + 34816;   // 2048
  _Float16* hxB2 = wp + 36864;   // 4096
  _Float16* feB1 = wp + 40960;   // 4096
  _Float16* feB2 = wp + 45056;   // 4096
  int which, id;
  _Float16* oh;
  if (tid < 1536)      { which = 0; id = tid;        oh = fxB1; }
  else if (tid < 2048) { which = 1; id = tid - 1536; oh = fxB2; }
  else if (tid < 3072) { which = 2; id = tid - 2048; oh = fyB1; }
  else if (tid < 3584) { which = 3; id = tid - 3072; oh = fyB2; }
  else if (tid < 3840) { which = 4; id = tid - 3584; oh = hyB1; }
  else if (tid < 4352) { which = 5; id = tid - 3840; oh = hyB2; }
  else if (tid < 4608) { which = 6; id = tid - 4352; oh = hxB1; }
  else if (tid < 5120) { which = 7; id = tid - 4608; oh = hxB2; }
  else if (tid < 5632) { which = 8; id = tid - 5120; oh = feB1; }
  else if (tid < 6144) { which = 9; id = tid - 5632; oh = feB2; }
  else return;
  int lane = id & 63;
  int q = lane >> 4, col = lane & 15;
  int c = id >> 8, t = (id >> 6) & 3;
#pragma unroll
  for (int j = 0; j < 8; ++j) {
    int k = c * 32 + q * 8 + j;
    int n = t * 16 + col;
    float w;
    if (which == 0) {
      w = (k < 64)  ? fxw1[k * 64 + n] + fxw1[(k + 64) * 64 + n]
        : (k < 128) ? fxw1[(k + 64) * 64 + n] - fxw1[(k - 64) * 64 + n]
                    : fxw1[(k + 64) * 64 + n];
    } else if (which == 1) {
      w = fxw2[k * 64 + n];
    } else if (which == 2) {
      w = (k < 64) ? fyw1[k * 64 + n] + fyw1[(k + 64) * 64 + n]
                   : fyw1[(k + 64) * 64 + n] - fyw1[(k - 64) * 64 + n];
    } else if (which == 3) {
      w = fyw2[k * 64 + n];
    } else if (which == 4) {
      if (k <= 8)                  w = hyw1[k * 64 + n] + hyw1[(k + 9) * 64 + n];
      else if (k >= 16 && k <= 24) w = hyw1[(k + 2) * 64 + n] - hyw1[(k - 16) * 64 + n];
      else                         w = 0.f;
    } else if (which == 5) {
      w = hyw2[k * 64 + n];
    } else if (which == 6) {
      w = (k < 9) ? hxw1[k * 64 + n] : (k < 27) ? hxw1[(k + 9) * 64 + n] : 0.f;
    } else if (which == 7) {
      w = hxw2[k * 64 + n];
    } else if (which == 8) {
      w = few1[k * 64 + n];
    } else {
      w = few2[k * 64 + n];
    }
    oh[id * 8 + j] = (_Float16)w;
  }
}

// ---------------- scan1 + goal2b merged (both depend only on k_vch) ----------------
__global__ __launch_bounds__(256) void k_scan1g(const int* __restrict__ deg, int N, int SB,
                                                int* __restrict__ bsum,
                                                const float* __restrict__ v,
                                                const float* __restrict__ labels,
                                                const u64* __restrict__ key,
                                                const float* __restrict__ hxw1,
                                                const float* __restrict__ hxb1,
                                                float* __restrict__ goal, float* __restrict__ b1p) {
  int b = blockIdx.x;
  if (b >= SB) {
    __shared__ float g[9];
    int gi = (int)(~(u32)(*key));
    int c = threadIdx.x;
    if (c < 9) {
      float gv = (c < 7) ? v[7 * (size_t)gi + c] : labels[2 * (size_t)gi + (c - 7)];
      g[c] = gv;
      goal[c] = gv;
    }
    __syncthreads();
    if (c < 64) {
      float s = hxb1[c];
#pragma unroll
      for (int k = 0; k < 9; ++k) s += g[k] * hxw1[(9 + k) * 64 + c];
      b1p[c] = s;
    }
    return;
  }
  __shared__ int red[256];
  int s = 0;
  for (int i = threadIdx.x; i < 1024; i += 256) {
    int idx = b * 1024 + i;
    s += (idx < N) ? deg[idx] : 0;
  }
  red[threadIdx.x] = s; __syncthreads();
  for (int st = 128; st > 0; st >>= 1) {
    if (threadIdx.x < st) red[threadIdx.x] += red[threadIdx.x + st];
    __syncthreads();
  }
  if (threadIdx.x == 0) bsum[b] = red[0];
}

// ---------------- hx (MFMA) + scan3 merged ----------------
__global__ __launch_bounds__(256) void k_hx2s(
    const float* __restrict__ vcp, const float* __restrict__ goal,
    const _Float16* __restrict__ B1, const float* __restrict__ b1p,
    const _Float16* __restrict__ B2, const float* __restrict__ b2,
    float* __restrict__ xout, _Float16* __restrict__ xh, int N,
    const int* __restrict__ deg, const int* __restrict__ bsum, int* __restrict__ cursor, int NB) {
  if ((int)blockIdx.x >= NB) {
    // ---- scan3 ----
    __shared__ int lsum[256];
    __shared__ int bofs;
    int b = blockIdx.x - NB;
    int tid = threadIdx.x;
    if (tid == 0) {
      int a = 0;
      for (int i = 0; i < b; ++i) a += bsum[i];
      bofs = a;
    }
    int base_i = b * 1024 + tid * 4;
    int loc[4]; int s = 0;
#pragma unroll
    for (int j = 0; j < 4; ++j) {
      int vv = (base_i + j < N) ? deg[base_i + j] : 0;
      loc[j] = s; s += vv;
    }
    lsum[tid] = s; __syncthreads();
    for (int st = 1; st < 256; st <<= 1) {
      int add = (tid >= st) ? lsum[tid - st] : 0;
      __syncthreads();
      lsum[tid] += add;
      __syncthreads();
    }
    int toff = bofs + lsum[tid] - s;
#pragma unroll
    for (int j = 0; j < 4; ++j) {
      if (base_i + j < N) cursor[base_i + j] = toff + loc[j];
    }
    return;
  }
  // ---- hx ---- (fp32 LDS: hi/lo decomposition needs full precision)
  __shared__ float hbuf[4][16 * 68];
  const int lane = threadIdx.x & 63;
  const int wv = threadIdx.x >> 6;
  const int m = lane & 15, q = lane >> 4;
  const int base = blockIdx.x * 64 + wv * 16;
  int node = base + m; if (node >= N) node = N - 1;
  float vc[12];
  *(float4*)(vc + 0) = *(const float4*)(vcp + (size_t)node * 16);
  *(float4*)(vc + 4) = *(const float4*)(vcp + (size_t)node * 16 + 4);
  *(float4*)(vc + 8) = *(const float4*)(vcp + (size_t)node * 16 + 8);
  float gl[9];
#pragma unroll
  for (int i = 0; i < 9; ++i) gl[i] = goal[i];
  float f[8];
#pragma unroll
  for (int j = 0; j < 8; ++j) {
    int idx = q * 8 + j;
    float val = 0.f;
    if (idx < 9) val = vc[idx];
    else if (idx < 18) val = vc[idx - 9] - gl[idx - 9];
    else if (idx < 27) { float dv = vc[idx - 18] - gl[idx - 18]; val = dv * dv; }
    f[j] = val;
  }
  U8h Ah, Al;
  dec8h(f, Ah, Al);

  f32x4 acc[4];
#pragma unroll
  for (int t = 0; t < 4; ++t) { float bv = b1p[t * 16 + m]; acc[t] = (f32x4){bv, bv, bv, bv}; }
#pragma unroll
  for (int t = 0; t < 4; ++t) {
    f16x8 b = *(const f16x8*)(B1 + ((size_t)t * 64 + lane) * 8);
    acc[t] = __builtin_amdgcn_mfma_f32_16x16x32_f16(Ah.v, b, acc[t], 0, 0, 0);
    acc[t] = __builtin_amdgcn_mfma_f32_16x16x32_f16(Al.v, b, acc[t], 0, 0, 0);
  }

  float* hb = hbuf[wv];
#pragma unroll
  for (int t = 0; t < 4; ++t)
#pragma unroll
    for (int r = 0; r < 4; ++r)
      hb[(q * 4 + r) * 68 + t * 16 + m] = fmaxf(acc[t][r], 0.f);

  float fh[16];
  load_row(hb + m * 68 + q * 8, fh);
  U8h A2h[2], A2l[2];
  dec8h(fh + 0, A2h[0], A2l[0]);
  dec8h(fh + 8, A2h[1], A2l[1]);

  f32x4 acc2[4];
#pragma unroll
  for (int t = 0; t < 4; ++t) { float bv = b2[t * 16 + m]; acc2[t] = (f32x4){bv, bv, bv, bv}; }
#pragma unroll
  for (int c = 0; c < 2; ++c) {
#pragma unroll
    for (int t = 0; t < 4; ++t) {
      f16x8 b = *(const f16x8*)(B2 + ((size_t)(c * 4 + t) * 64 + lane) * 8);
      acc2[t] = __builtin_amdgcn_mfma_f32_16x16x32_f16(A2h[c].v, b, acc2[t], 0, 0, 0);
      acc2[t] = __builtin_amdgcn_mfma_f32_16x16x32_f16(A2l[c].v, b, acc2[t], 0, 0, 0);
    }
  }

#pragma unroll
  for (int t = 0; t < 4; ++t)
#pragma unroll
    for (int r = 0; r < 4; ++r)
      hb[(q * 4 + r) * 68 + t * 16 + m] = acc2[t][r];

  int row = base + m;
  if (row < N) {
    float ov[16];
    const float* orow = hb + m * 68 + q * 16;
    *(float4*)(ov + 0)  = *(const float4*)(orow);
    *(float4*)(ov + 4)  = *(const float4*)(orow + 4);
    *(float4*)(ov + 8)  = *(const float4*)(orow + 8);
    *(float4*)(ov + 12) = *(const float4*)(orow + 12);
    float* p1 = xout + (size_t)row * 64 + q * 16;
#pragma unroll
    for (int i = 0; i < 4; ++i) {
      *(float4*)(p1 + i * 4) = *(const float4*)(ov + i * 4);
    }
    U8h X0, X1;
    conv8_rne(ov + 0, X0);
    conv8_rne(ov + 8, X1);
    *(f16x8*)(xh + (size_t)row * 64 + q * 16)     = X0.v;
    *(f16x8*)(xh + (size_t)row * 64 + q * 16 + 8) = X1.v;
  }
}

__global__ __launch_bounds__(256) void k_scatter(const int* __restrict__ src,
                                                 const int* __restrict__ dst, int E,
                                                 int* __restrict__ cursor,
                                                 int* __restrict__ srcp, int* __restrict__ dstp) {
  int e = blockIdx.x * 256 + threadIdx.x;
  if (e < E) {
    int d = dst[e];
    int pos = atomicAdd(&cursor[d], 1);
    srcp[pos] = src[e];
    dstp[pos] = d;
  }
}

// ---------------- convert: fp16 gather shadow from fp32 x (in-place atomics; no copy) ----------------
__global__ __launch_bounds__(256) void k_ch(const float4* __restrict__ s,
                                            _Float16* __restrict__ h16, int n4) {
  int i = blockIdx.x * 256 + threadIdx.x;
  if (i < n4) {
    float4 v = s[i];
    U4h o;
    o.s[0] = (_Float16)v.x; o.s[1] = (_Float16)v.y;
    o.s[2] = (_Float16)v.z; o.s[3] = (_Float16)v.w;
    *(u64*)(h16 + (size_t)i * 4) = o.u;
  }
}

// ---------------- fused hy + fx (t=0): 2 tiles/wave, fp16 LDS transposes ----------------
// All three LDS round-trips feed fp16 MFMA fragments, so storing fp16 (RNE before
// write instead of after read) is numerically identical and halves LDS footprint:
// 8 slices x 16x72 fp16 = 18432 B/block (stride 72 keeps f16x8 reads 16B-aligned).
__global__ __launch_bounds__(256) void k_hyfx(
    const float* __restrict__ vcp, const _Float16* __restrict__ xh,
    const int* __restrict__ src, const int* __restrict__ dst,
    const _Float16* __restrict__ hB1, const float* __restrict__ hb1,
    const _Float16* __restrict__ hB2, const float* __restrict__ hb2,
    const _Float16* __restrict__ xB1, const float* __restrict__ xb1,
    const _Float16* __restrict__ xB2, const float* __restrict__ xb2,
    _Float16* __restrict__ y, float* __restrict__ xnew, int E) {
  __shared__ __align__(16) _Float16 hbuf[8][16 * 72];
  const int lane = threadIdx.x & 63;
  const int wv = threadIdx.x >> 6;
  const int m = lane & 15, q = lane >> 4;
  const int b0e = blockIdx.x * 128 + wv * 16;
  _Float16* hb0 = hbuf[wv];
  _Float16* hbx = hbuf[4 + wv];

  int em0 = b0e + m;       if (em0 >= E) em0 = E - 1;
  int em1 = b0e + 64 + m;  if (em1 >= E) em1 = E - 1;
  const int si0 = src[em0], di0 = dst[em0];
  const int si1 = src[em1], di1 = dst[em1];
  const bool live0 = (b0e + m) < E;
  const bool live1 = (b0e + 64 + m) < E;

  U8h Xs0[2], Xs1[2], Xd0[2], Xd1[2];
  {
    const _Float16* ps = xh + (size_t)si0 * 64 + q * 8;
    const _Float16* pd = xh + (size_t)di0 * 64 + q * 8;
    Xs0[0].v = *(const f16x8*)ps;  Xs1[0].v = *(const f16x8*)(ps + 32);
    Xd0[0].v = *(const f16x8*)pd;  Xd1[0].v = *(const f16x8*)(pd + 32);
  }
  {
    const _Float16* ps = xh + (size_t)si1 * 64 + q * 8;
    const _Float16* pd = xh + (size_t)di1 * 64 + q * 8;
    Xs0[1].v = *(const f16x8*)ps;  Xs1[1].v = *(const f16x8*)(ps + 32);
    Xd0[1].v = *(const f16x8*)pd;  Xd1[1].v = *(const f16x8*)(pd + 32);
  }

  // hy A inputs (vcp of di for q<2, si for q>=2)
  U8h Ah[2], Al[2];
  {
    const int n0 = (q < 2) ? di0 : si0;
    const float* p = vcp + (size_t)n0 * 16 + (q & 1) * 8;
    float f[8];
    *(float4*)(f + 0) = *(const float4*)(p);
    *(float4*)(f + 4) = *(const float4*)(p + 4);
    dec8h(f, Ah[0], Al[0]);
  }
  {
    const int n1 = (q < 2) ? di1 : si1;
    const float* p = vcp + (size_t)n1 * 16 + (q & 1) * 8;
    float f[8];
    *(float4*)(f + 0) = *(const float4*)(p);
    *(float4*)(f + 4) = *(const float4*)(p + 4);
    dec8h(f, Ah[1], Al[1]);
  }

  // ---- hy layer 1 ----
  f32x4 acc[2][4];
#pragma unroll
  for (int t = 0; t < 4; ++t) {
    float bv = hb1[t * 16 + m];
    acc[0][t] = (f32x4){bv, bv, bv, bv};
    acc[1][t] = acc[0][t];
  }
#pragma unroll
  for (int t = 0; t < 4; ++t) {
    f16x8 w = *(const f16x8*)(hB1 + ((size_t)t * 64 + lane) * 8);
#pragma unroll
    for (int u = 0; u < 2; ++u) {
      acc[u][t] = __builtin_amdgcn_mfma_f32_16x16x32_f16(Ah[u].v, w, acc[u][t], 0, 0, 0);
      acc[u][t] = __builtin_amdgcn_mfma_f32_16x16x32_f16(Al[u].v, w, acc[u][t], 0, 0, 0);
    }
  }

#pragma unroll
  for (int t = 0; t < 4; ++t)
#pragma unroll
    for (int r = 0; r < 4; ++r) {
      hb0[(q * 4 + r) * 72 + t * 16 + m] = (_Float16)fmaxf(acc[0][t][r], 0.f);
      hbx[(q * 4 + r) * 72 + t * 16 + m] = (_Float16)fmaxf(acc[1][t][r], 0.f);
    }

  U8h H0[2], H1[2];
  H0[0].v = *(const f16x8*)(hb0 + m * 72 + q * 8);
  H1[0].v = *(const f16x8*)(hb0 + m * 72 + q * 8 + 32);
  H0[1].v = *(const f16x8*)(hbx + m * 72 + q * 8);
  H1[1].v = *(const f16x8*)(hbx + m * 72 + q * 8 + 32);

  // ---- hy layer 2 ----
  f32x4 o[2][4];
#pragma unroll
  for (int t = 0; t < 4; ++t) {
    float bv = hb2[t * 16 + m];
    o[0][t] = (f32x4){bv, bv, bv, bv};
    o[1][t] = o[0][t];
  }
#pragma unroll
  for (int t = 0; t < 4; ++t) {
    f16x8 w0 = *(const f16x8*)(hB2 + ((size_t)(0 * 4 + t) * 64 + lane) * 8);
    f16x8 w1 = *(const f16x8*)(hB2 + ((size_t)(1 * 4 + t) * 64 + lane) * 8);
#pragma unroll
    for (int u = 0; u < 2; ++u) {
      o[u][t] = __builtin_amdgcn_mfma_f32_16x16x32_f16(H0[u].v, w0, o[u][t], 0, 0, 0);
      o[u][t] = __builtin_amdgcn_mfma_f32_16x16x32_f16(H1[u].v, w1, o[u][t], 0, 0, 0);
    }
  }

#pragma unroll
  for (int t = 0; t < 4; ++t)
#pragma unroll
    for (int r = 0; r < 4; ++r) {
      hb0[(q * 4 + r) * 72 + t * 16 + m] = (_Float16)o[0][t][r];
      hbx[(q * 4 + r) * 72 + t * 16 + m] = (_Float16)o[1][t][r];
    }

  U8h Yh0[2], Yh1[2];
  Yh0[0].v = *(const f16x8*)(hb0 + m * 72 + q * 8);
  Yh1[0].v = *(const f16x8*)(hb0 + m * 72 + q * 8 + 32);
  Yh0[1].v = *(const f16x8*)(hbx + m * 72 + q * 8);
  Yh1[1].v = *(const f16x8*)(hbx + m * 72 + q * 8 + 32);
  if (live0) {
    size_t yo = (size_t)(b0e + m) * 64 + q * 8;
    *(f16x8*)(y + yo)      = Yh0[0].v;
    *(f16x8*)(y + yo + 32) = Yh1[0].v;
  }
  if (live1) {
    size_t yo = (size_t)(b0e + 64 + m) * 64 + q * 8;
    *(f16x8*)(y + yo)      = Yh0[1].v;
    *(f16x8*)(y + yo + 32) = Yh1[1].v;
  }

  // ---- fx layer 1 ----
  f32x4 acc2[2][4];
#pragma unroll
  for (int t = 0; t < 4; ++t) {
    float bv = xb1[t * 16 + m];
    acc2[0][t] = (f32x4){bv, bv, bv, bv};
    acc2[1][t] = acc2[0][t];
  }
#pragma unroll
  for (int t = 0; t < 4; ++t) {
    f16x8 w0 = *(const f16x8*)(xB1 + ((size_t)(0 * 4 + t) * 64 + lane) * 8);
    f16x8 w1 = *(const f16x8*)(xB1 + ((size_t)(1 * 4 + t) * 64 + lane) * 8);
    f16x8 w2 = *(const f16x8*)(xB1 + ((size_t)(2 * 4 + t) * 64 + lane) * 8);
    f16x8 w3 = *(const f16x8*)(xB1 + ((size_t)(3 * 4 + t) * 64 + lane) * 8);
    f16x8 w4 = *(const f16x8*)(xB1 + ((size_t)(4 * 4 + t) * 64 + lane) * 8);
    f16x8 w5 = *(const f16x8*)(xB1 + ((size_t)(5 * 4 + t) * 64 + lane) * 8);
#pragma unroll
    for (int u = 0; u < 2; ++u) {
      acc2[u][t] = __builtin_amdgcn_mfma_f32_16x16x32_f16(Xs0[u].v, w0, acc2[u][t], 0, 0, 0);
      acc2[u][t] = __builtin_amdgcn_mfma_f32_16x16x32_f16(Xs1[u].v, w1, acc2[u][t], 0, 0, 0);
      acc2[u][t] = __builtin_amdgcn_mfma_f32_16x16x32_f16(Xd0[u].v, w2, acc2[u][t], 0, 0, 0);
      acc2[u][t] = __builtin_amdgcn_mfma_f32_16x16x32_f16(Xd1[u].v, w3, acc2[u][t], 0, 0, 0);
      acc2[u][t] = __builtin_amdgcn_mfma_f32_16x16x32_f16(Yh0[u].v, w4, acc2[u][t], 0, 0, 0);
      acc2[u][t] = __builtin_amdgcn_mfma_f32_16x16x32_f16(Yh1[u].v, w5, acc2[u][t], 0, 0, 0);
    }
  }

#pragma unroll
  for (int t = 0; t < 4; ++t)
#pragma unroll
    for (int r = 0; r < 4; ++r) {
      hb0[(q * 4 + r) * 72 + t * 16 + m] = (_Float16)fmaxf(acc2[0][t][r], 0.f);
      hbx[(q * 4 + r) * 72 + t * 16 + m] = (_Float16)fmaxf(acc2[1][t][r], 0.f);
    }

  U8h G0[2], G1[2];
  G0[0].v = *(const f16x8*)(hb0 + m * 72 + q * 8);
  G1[0].v = *(const f16x8*)(hb0 + m * 72 + q * 8 + 32);
  G0[1].v = *(const f16x8*)(hbx + m * 72 + q * 8);
  G1[1].v = *(const f16x8*)(hbx + m * 72 + q * 8 + 32);

  // dst loads for emit (deferred)
  int dd0[4], dd1[4];
  {
    int e0 = b0e + q * 4;
#pragma unroll
    for (int r = 0; r < 4; ++r) {
      int e2 = e0 + r;
      dd0[r] = (e2 < E) ? dst[e2] : -1;
      int e3 = e2 + 64;
      dd1[r] = (e3 < E) ? dst[e3] : -1;
    }
  }

  // ---- fx layer 2 ----
  f32x4 o2[2][4];
#pragma unroll
  for (int t = 0; t < 4; ++t) {
    float bv = xb2[t * 16 + m];
    o2[0][t] = (f32x4){bv, bv, bv, bv};
    o2[1][t] = o2[0][t];
  }
#pragma unroll
  for (int t = 0; t < 4; ++t) {
    f16x8 w0 = *(const f16x8*)(xB2 + ((size_t)(0 * 4 + t) * 64 + lane) * 8);
    f16x8 w1 = *(const f16x8*)(xB2 + ((size_t)(1 * 4 + t) * 64 + lane) * 8);
#pragma unroll
    for (int u = 0; u < 2; ++u) {
      o2[u][t] = __builtin_amdgcn_mfma_f32_16x16x32_f16(G0[u].v, w0, o2[u][t], 0, 0, 0);
      o2[u][t] = __builtin_amdgcn_mfma_f32_16x16x32_f16(G1[u].v, w1, o2[u][t], 0, 0, 0);
    }
  }

  RunCtx rc0 = run_ctx(dd0, lane, q);
#pragma unroll
  for (int t = 0; t < 4; ++t) emit_t(o2[0][t], dd0, rc0, lane, m, t, xnew);
  RunCtx rc1 = run_ctx(dd1, lane, q);
#pragma unroll
  for (int t = 0; t < 4; ++t) emit_t(o2[1][t], dd1, rc1, lane, m, t, xnew);
}

// ---------------- fused fy + fx (t=1,2): 2 tiles/wave, fp16 LDS transposes ----------------
__global__ __launch_bounds__(256) void k_fyfx(
    const _Float16* __restrict__ xh, _Float16* __restrict__ y,
    const int* __restrict__ src, const int* __restrict__ dst,
    const _Float16* __restrict__ yB1, const float* __restrict__ yb1,
    const _Float16* __restrict__ yB2, const float* __restrict__ yb2,
    const _Float16* __restrict__ xB1, const float* __restrict__ xb1,
    const _Float16* __restrict__ xB2, const float* __restrict__ xb2,
    float* __restrict__ xnew, int E, int storeY) {
  __shared__ __align__(16) _Float16 hbuf[8][16 * 72];
  const int lane = threadIdx.x & 63;
  const int wv = threadIdx.x >> 6;
  const int m = lane & 15, q = lane >> 4;
  const int b0e = blockIdx.x * 128 + wv * 16;
  _Float16* hb0 = hbuf[wv];
  _Float16* hbx = hbuf[4 + wv];

  int em0 = b0e + m;       if (em0 >= E) em0 = E - 1;
  int em1 = b0e + 64 + m;  if (em1 >= E) em1 = E - 1;
  const int si0 = src[em0], di0 = dst[em0];
  const int si1 = src[em1], di1 = dst[em1];
  const bool live0 = (b0e + m) < E;
  const bool live1 = (b0e + 64 + m) < E;

  U8h Xs0[2], Xs1[2], Xd0[2], Xd1[2], Ho0[2], Ho1[2];
  {
    const _Float16* ps = xh + (size_t)si0 * 64 + q * 8;
    const _Float16* pd = xh + (size_t)di0 * 64 + q * 8;
    Xs0[0].v = *(const f16x8*)ps;  Xs1[0].v = *(const f16x8*)(ps + 32);
    Xd0[0].v = *(const f16x8*)pd;  Xd1[0].v = *(const f16x8*)(pd + 32);
  }
  {
    const _Float16* ps = xh + (size_t)si1 * 64 + q * 8;
    const _Float16* pd = xh + (size_t)di1 * 64 + q * 8;
    Xs0[1].v = *(const f16x8*)ps;  Xs1[1].v = *(const f16x8*)(ps + 32);
    Xd0[1].v = *(const f16x8*)pd;  Xd1[1].v = *(const f16x8*)(pd + 32);
  }
  {
    size_t yo0 = (size_t)em0 * 64 + q * 8;
    size_t yo1 = (size_t)em1 * 64 + q * 8;
    Ho0[0].v = *(const f16x8*)(y + yo0);  Ho1[0].v = *(const f16x8*)(y + yo0 + 32);
    Ho0[1].v = *(const f16x8*)(y + yo1);  Ho1[1].v = *(const f16x8*)(y + yo1 + 32);
  }

  // ---- fy layer 1 ----
  f32x4 acc[2][4];
#pragma unroll
  for (int t = 0; t < 4; ++t) {
    float bv = yb1[t * 16 + m];
    acc[0][t] = (f32x4){bv, bv, bv, bv};
    acc[1][t] = acc[0][t];
  }
#pragma unroll
  for (int t = 0; t < 4; ++t) {
    f16x8 w0 = *(const f16x8*)(yB1 + ((size_t)(0 * 4 + t) * 64 + lane) * 8);
    f16x8 w1 = *(const f16x8*)(yB1 + ((size_t)(1 * 4 + t) * 64 + lane) * 8);
    f16x8 w2 = *(const f16x8*)(yB1 + ((size_t)(2 * 4 + t) * 64 + lane) * 8);
    f16x8 w3 = *(const f16x8*)(yB1 + ((size_t)(3 * 4 + t) * 64 + lane) * 8);
#pragma unroll
    for (int u = 0; u < 2; ++u) {
      acc[u][t] = __builtin_amdgcn_mfma_f32_16x16x32_f16(Xd0[u].v, w0, acc[u][t], 0, 0, 0);
      acc[u][t] = __builtin_amdgcn_mfma_f32_16x16x32_f16(Xd1[u].v, w1, acc[u][t], 0, 0, 0);
      acc[u][t] = __builtin_amdgcn_mfma_f32_16x16x32_f16(Xs0[u].v, w2, acc[u][t], 0, 0, 0);
      acc[u][t] = __builtin_amdgcn_mfma_f32_16x16x32_f16(Xs1[u].v, w3, acc[u][t], 0, 0, 0);
    }
  }

#pragma unroll
  for (int t = 0; t < 4; ++t)
#pragma unroll
    for (int r = 0; r < 4; ++r) {
      hb0[(q * 4 + r) * 72 + t * 16 + m] = (_Float16)fmaxf(acc[0][t][r], 0.f);
      hbx[(q * 4 + r) * 72 + t * 16 + m] = (_Float16)fmaxf(acc[1][t][r], 0.f);
    }

  U8h H0[2], H1[2];
  H0[0].v = *(const f16x8*)(hb0 + m * 72 + q * 8);
  H1[0].v = *(const f16x8*)(hb0 + m * 72 + q * 8 + 32);
  H0[1].v = *(const f16x8*)(hbx + m * 72 + q * 8);
  H1[1].v = *(const f16x8*)(hbx + m * 72 + q * 8 + 32);

  // ---- fy layer 2 ----
  f32x4 o[2][4];
#pragma unroll
  for (int t = 0; t < 4; ++t) {
    float bv = yb2[t * 16 + m];
    o[0][t] = (f32x4){bv, bv, bv, bv};
    o[1][t] = o[0][t];
  }
#pragma unroll
  for (int t = 0; t < 4; ++t) {
    f16x8 w0 = *(const f16x8*)(yB2 + ((size_t)(0 * 4 + t) * 64 + lane) * 8);
    f16x8 w1 = *(const f16x8*)(yB2 + ((size_t)(1 * 4 + t) * 64 + lane) * 8);
#pragma unroll
    for (int u = 0; u < 2; ++u) {
      o[u][t] = __builtin_amdgcn_mfma_f32_16x16x32_f16(H0[u].v, w0, o[u][t], 0, 0, 0);
      o[u][t] = __builtin_amdgcn_mfma_f32_16x16x32_f16(H1[u].v, w1, o[u][t], 0, 0, 0);
    }
  }

#pragma unroll
  for (int t = 0; t < 4; ++t)
#pragma unroll
    for (int r = 0; r < 4; ++r) {
      hb0[(q * 4 + r) * 72 + t * 16 + m] = (_Float16)o[0][t][r];
      hbx[(q * 4 + r) * 72 + t * 16 + m] = (_Float16)o[1][t][r];
    }

  // y-new = max(y-old, fy2-out) computed in fp16 (RNE monotone: exact vs fp32-max-then-round)
  U8h Yh0[2], Yh1[2];
  Yh0[0].v = hmax8(*(const f16x8*)(hb0 + m * 72 + q * 8),      Ho0[0].v);
  Yh1[0].v = hmax8(*(const f16x8*)(hb0 + m * 72 + q * 8 + 32), Ho1[0].v);
  Yh0[1].v = hmax8(*(const f16x8*)(hbx + m * 72 + q * 8),      Ho0[1].v);
  Yh1[1].v = hmax8(*(const f16x8*)(hbx + m * 72 + q * 8 + 32), Ho1[1].v);
  if (storeY) {
    if (live0) {
      size_t yo = (size_t)(b0e + m) * 64 + q * 8;
      *(f16x8*)(y + yo)      = Yh0[0].v;
      *(f16x8*)(y + yo + 32) = Yh1[0].v;
    }
    if (live1) {
      size_t yo = (size_t)(b0e + 64 + m) * 64 + q * 8;
      *(f16x8*)(y + yo)      = Yh0[1].v;
      *(f16x8*)(y + yo + 32) = Yh1[1].v;
    }
  }

  // ---- fx layer 1 ----
  f32x4 acc2[2][4];
#pragma unroll
  for (int t = 0; t < 4; ++t) {
    float bv = xb1[t * 16 + m];
    acc2[0][t] = (f32x4){bv, bv, bv, bv};
    acc2[1][t] = acc2[0][t];
  }
#pragma unroll
  for (int t = 0; t < 4; ++t) {
    f16x8 w0 = *(const f16x8*)(xB1 + ((size_t)(0 * 4 + t) * 64 + lane) * 8);
    f16x8 w1 = *(const f16x8*)(xB1 + ((size_t)(1 * 4 + t) * 64 + lane) * 8);
    f16x8 w2 = *(const f16x8*)(xB1 + ((size_t)(2 * 4 + t) * 64 + lane) * 8);
    f16x8 w3 = *(const f16x8*)(xB1 + ((size_t)(3 * 4 + t) * 64 + lane) * 8);
    f16x8 w4 = *(const f16x8*)(xB1 + ((size_t)(4 * 4 + t) * 64 + lane) * 8);
    f16x8 w5 = *(const f16x8*)(xB1 + ((size_t)(5 * 4 + t) * 64 + lane) * 8);
#pragma unroll
    for (int u = 0; u < 2; ++u) {
      acc2[u][t] = __builtin_amdgcn_mfma_f32_16x16x32_f16(Xs0[u].v, w0, acc2[u][t], 0, 0, 0);
      acc2[u][t] = __builtin_amdgcn_mfma_f32_16x16x32_f16(Xs1[u].v, w1, acc2[u][t], 0, 0, 0);
      acc2[u][t] = __builtin_amdgcn_mfma_f32_16x16x32_f16(Xd0[u].v, w2, acc2[u][t], 0, 0, 0);
      acc2[u][t] = __builtin_amdgcn_mfma_f32_16x16x32_f16(Xd1[u].v, w3, acc2[u][t], 0, 0, 0);
      acc2[u][t] = __builtin_amdgcn_mfma_f32_16x16x32_f16(Yh0[u].v, w4, acc2[u][t], 0, 0, 0);
      acc2[u][t] = __builtin_amdgcn_mfma_f32_16x16x32_f16(Yh1[u].v, w5, acc2[u][t], 0, 0, 0);
    }
  }

#pragma unroll
  for (int t = 0; t < 4; ++t)
#pragma unroll
    for (int r = 0; r < 4; ++r) {
      hb0[(q * 4 + r) * 72 + t * 16 + m] = (_Float16)fmaxf(acc2[0][t][r], 0.f);
      hbx[(q * 4 + r) * 72 + t * 16 + m] = (_Float16)fmaxf(acc2[1][t][r], 0.f);
    }

  U8h G0[2], G1[2];
  G0[0].v = *(const f16x8*)(hb0 + m * 72 + q * 8);
  G1[0].v = *(const f16x8*)(hb0 + m * 72 + q * 8 + 32);
  G0[1].v = *(const f16x8*)(hbx + m * 72 + q * 8);
  G1[1].v = *(const f16x8*)(hbx + m * 72 + q * 8 + 32);

  // dst loads for emit (deferred to shorten register lifetimes)
  int dd0[4], dd1[4];
  {
    int e0 = b0e + q * 4;
#pragma unroll
    for (int r = 0; r < 4; ++r) {
      int e2 = e0 + r;
      dd0[r] = (e2 < E) ? dst[e2] : -1;
      int e3 = e2 + 64;
      dd1[r] = (e3 < E) ? dst[e3] : -1;
    }
  }

  // ---- fx layer 2 ----
  f32x4 o2[2][4];
#pragma unroll
  for (int t = 0; t < 4; ++t) {
    float bv = xb2[t * 16 + m];
    o2[0][t] = (f32x4){bv, bv, bv, bv};
    o2[1][t] = o2[0][t];
  }
#pragma unroll
  for (int t = 0; t < 4; ++t) {
    f16x8 w0 = *(const f16x8*)(xB2 + ((size_t)(0 * 4 + t) * 64 + lane) * 8);
    f16x8 w1 = *(const f16x8*)(xB2 + ((size_t)(1 * 4 + t) * 64 + lane) * 8);
#pragma unroll
    for (int u = 0; u < 2; ++u) {
      o2[u][t] = __builtin_amdgcn_mfma_f32_16x16x32_f16(G0[u].v, w0, o2[u][t], 0, 0, 0);
      o2[u][t] = __builtin_amdgcn_mfma_f32_16x16x32_f16(G1[u].v, w1, o2[u][t], 0, 0, 0);
    }
  }

  RunCtx rc0 = run_ctx(dd0, lane, q);
#pragma unroll
  for (int t = 0; t < 4; ++t) emit_t(o2[0][t], dd0, rc0, lane, m, t, xnew);
  RunCtx rc1 = run_ctx(dd1, lane, q);
#pragma unroll
  for (int t = 0; t < 4; ++t) emit_t(o2[1][t], dd1, rc1, lane, m, t, xnew);
}

// ---------------- feta (MFMA): out = w3 . relu(MLP2(x)) ----------------
__global__ __launch_bounds__(256) void k_feta2(
    const float* __restrict__ x,
    const _Float16* __restrict__ B1, const float* __restrict__ b1,
    const _Float16* __restrict__ B2, const float* __restrict__ b2,
    const float* __restrict__ w3, float* __restrict__ out, int N) {
  __shared__ float hbuf[4][16 * 68];
  const int lane = threadIdx.x & 63;
  const int wv = threadIdx.x >> 6;
  const int m = lane & 15, q = lane >> 4;
  const int base = blockIdx.x * 64 + wv * 16;
  int node = base + m; if (node >= N) node = N - 1;
  float fs[16];
  load_row(x + (size_t)node * 64 + q * 8, fs);
  U8h Ah[2], Al[2];
  dec8h(fs + 0, Ah[0], Al[0]);
  dec8h(fs + 8, Ah[1], Al[1]);

  f32x4 acc[4];
#pragma unroll
  for (int t = 0; t < 4; ++t) { float bv = b1[t * 16 + m]; acc[t] = (f32x4){bv, bv, bv, bv}; }
#pragma unroll
  for (int c = 0; c < 2; ++c) {
#pragma unroll
    for (int t = 0; t < 4; ++t) {
      f16x8 b = *(const f16x8*)(B1 + ((size_t)(c * 4 + t) * 64 + lane) * 8);
      acc[t] = __builtin_amdgcn_mfma_f32_16x16x32_f16(Ah[c].v, b, acc[t], 0, 0, 0);
      acc[t] = __builtin_amdgcn_mfma_f32_16x16x32_f16(Al[c].v, b, acc[t], 0, 0, 0);
    }
  }

  float* hb = hbuf[wv];
#pragma unroll
  for (int t = 0; t < 4; ++t)
#pragma unroll
    for (int r = 0; r < 4; ++r)
      hb[(q * 4 + r) * 68 + t * 16 + m] = fmaxf(acc[t][r], 0.f);

  float fh[16];
  load_row(hb + m * 68 + q * 8, fh);
  U8h A2h[2], A2l[2];
  dec8h(fh + 0, A2h[0], A2l[0]);
  dec8h(fh + 8, A2h[1], A2l[1]);

  f32x4 acc2[4];
#pragma unroll
  for (int t = 0; t < 4; ++t) { float bv = b2[t * 16 + m]; acc2[t] = (f32x4){bv, bv, bv, bv}; }
#pragma unroll
  for (int c = 0; c < 2; ++c) {
#pragma unroll
    for (int t = 0; t < 4; ++t) {
      f16x8 b = *(const f16x8*)(B2 + ((size_t)(c * 4 + t) * 64 + lane) * 8);
      acc2[t] = __builtin_amdgcn_mfma_f32_16x16x32_f16(A2h[c].v, b, acc2[t], 0, 0, 0);
      acc2[t] = __builtin_amdgcn_mfma_f32_16x16x32_f16(A2l[c].v, b, acc2[t], 0, 0, 0);
    }
  }

  float w3v[4];
#pragma unroll
  for (int t = 0; t < 4; ++t) w3v[t] = w3[t * 16 + m];
#pragma unroll
  for (int r = 0; r < 4; ++r) {
    float s = 0.f;
#pragma unroll
    for (int t = 0; t < 4; ++t) s += fmaxf(acc2[t][r], 0.f) * w3v[t];
    s += __shfl_xor(s, 1, 64);
    s += __shfl_xor(s, 2, 64);
    s += __shfl_xor(s, 4, 64);
    s += __shfl_xor(s, 8, 64);
    int row = base + q * 4 + r;
    if (m == 0 && row < N) out[row] = s;
  }
}

extern "C" void kernel_launch(void* const* d_in, const int* in_sizes, int n_in,
                              void* d_out, int out_size, void* d_ws, size_t ws_size,
                              hipStream_t stream) {
  const float* v      = (const float*)d_in[0];
  const float* labels = (const float*)d_in[1];
  const int*   ei     = (const int*)d_in[2];
  const float* hx_w1 = (const float*)d_in[4];
  const float* hx_b1 = (const float*)d_in[5];
  const float* hx_w2 = (const float*)d_in[6];
  const float* hx_b2 = (const float*)d_in[7];
  const float* hy_w1 = (const float*)d_in[8];
  const float* hy_b1 = (const float*)d_in[9];
  const float* hy_w2 = (const float*)d_in[10];
  const float* hy_b2 = (const float*)d_in[11];
  const float* fx_w1 = (const float*)d_in[12];
  const float* fx_b1 = (const float*)d_in[13];
  const float* fx_w2 = (const float*)d_in[14];
  const float* fx_b2 = (const float*)d_in[15];
  const float* fy_w1 = (const float*)d_in[16];
  const float* fy_b1 = (const float*)d_in[17];
  const float* fy_w2 = (const float*)d_in[18];
  const float* fy_b2 = (const float*)d_in[19];
  const float* feta_w1 = (const float*)d_in[20];
  const float* feta_b1 = (const float*)d_in[21];
  const float* feta_w2 = (const float*)d_in[22];
  const float* feta_b2 = (const float*)d_in[23];
  const float* feta_w3 = (const float*)d_in[24];

  int N = in_sizes[0] / 7;
  int E = in_sizes[2] / 2;
  const int* src = ei;
  const int* dst = ei + E;

  char* wsb = (char*)d_ws;
  float* goal = (float*)wsb;                                     // 16 f
  u64* goalkey = (u64*)(wsb + 64);
  float* b1p = (float*)(wsb + 96);                               // 64 f
  float* x = (float*)(wsb + 512);                                // N*64 f (in-place across rounds)
  _Float16* xh = (_Float16*)(x + (size_t)N * 64);                // N*64 f16 gather shadow
  _Float16* y = xh + (size_t)N * 64;                             // E*64 f16
  _Float16* wp = y + (size_t)E * 64;                             // 49152 f16
  float* vcp = (float*)(wp + 49152);                             // N*16 f
  int* deg = (int*)(vcp + (size_t)N * 16);                       // N
  int* cursor = deg + N;                                         // N
  int* srcp = cursor + N;                                        // E
  int* dstp = srcp + E;                                          // E
  int* bsum = dstp + E;                                          // 64

  _Float16* fxB1 = wp;          _Float16* fxB2 = wp + 12288;
  _Float16* fyB1 = wp + 16384;  _Float16* fyB2 = wp + 24576;
  _Float16* hyB1 = wp + 28672;  _Float16* hyB2 = wp + 30720;
  _Float16* hxB1 = wp + 34816;  _Float16* hxB2 = wp + 36864;
  _Float16* feB1 = wp + 40960;  _Float16* feB2 = wp + 45056;

  int SB = (N + 1023) / 1024;
  int NB = (N + 63) / 64;
  int EB2 = (E + 127) / 128;

  // prep weights + zero deg/goalkey (one kernel, no memset)
  k_prep<<<25, 256, 0, stream>>>(fx_w1, fx_w2, fy_w1, fy_w2, hy_w1, hy_w2,
                                 hx_w1, hx_w2, feta_w1, feta_w2, wp, goalkey, deg, N);
  k_vch<<<(N * 16 + 255) / 256, 256, 0, stream>>>(v, labels, vcp, N, dst, E, deg, goalkey);
  // scan1 + goal2b (independent, merged)
  k_scan1g<<<SB + 1, 256, 0, stream>>>(deg, N, SB, bsum, v, labels, goalkey,
                                       hx_w1, hx_b1, goal, b1p);
  // hx (needs b1p) + scan3 (needs bsum) merged
  k_hx2s<<<NB + SB, 256, 0, stream>>>(vcp, goal, hxB1, b1p, hxB2, hx_b2, x, xh, N,
                                      deg, bsum, cursor, NB);
  k_scatter<<<(E + 255) / 256, 256, 0, stream>>>(src, dst, E, cursor, srcp, dstp);

  // t=0: y0 = hy(vcp); x2 = max(x1, agg fx(x1,y0)) in place
  k_hyfx<<<EB2, 256, 0, stream>>>(vcp, xh, srcp, dstp,
                                  hyB1, hy_b1, hyB2, hy_b2,
                                  fxB1, fx_b1, fxB2, fx_b2, y, x, E);
  // t=1 (refresh fp16 shadow, atomics in place)
  k_ch<<<(N * 16 + 255) / 256, 256, 0, stream>>>((const float4*)x, xh, N * 16);
  k_fyfx<<<EB2, 256, 0, stream>>>(xh, y, srcp, dstp,
                                  fyB1, fy_b1, fyB2, fy_b2,
                                  fxB1, fx_b1, fxB2, fx_b2, x, E, 1);
  // t=2 (y dead after: skip its store)
  k_ch<<<(N * 16 + 255) / 256, 256, 0, stream>>>((const float4*)x, xh, N * 16);
  k_fyfx<<<EB2, 256, 0, stream>>>(xh, y, srcp, dstp,
                                  fyB1, fy_b1, fyB2, fy_b2,
                                  fxB1, fx_b1, fxB2, fx_b2, x, E, 0);

  k_feta2<<<NB, 256, 0, stream>>>(x, feB1, feta_b1, feB2, feta_b2, feta_w3,
                                  (float*)d_out, N);
}